// Round 9
// baseline (446.390 us; speedup 1.0000x reference)
//
#include <hip/hip_runtime.h>
#include <cstddef>
#include <cstdint>

// Problem constants (match reference)
#define DMODEL 1024
#define DI     2048      // D_INNER
#define LSEQ   2048
#define NB     2
#define DSTATE 16
#define DTRANK 64
#define NXP    96        // DT_RANK + 2*D_STATE
#define MROWS  (NB*LSEQ) // 4096 GEMM rows
#define CHUNKS 32
#define LC     (LSEQ/CHUNKS)   // 64

typedef __attribute__((ext_vector_type(8))) short bf16x8;
typedef __attribute__((ext_vector_type(8))) unsigned short u16x8;
typedef __attribute__((ext_vector_type(4))) float f32x4;

__device__ __forceinline__ float silu_f(float v) {
  return v / (1.f + __expf(-v));
}
__device__ __forceinline__ float softplus_f(float v) {
  return (v > 20.f) ? v : log1pf(__expf(v));
}
__device__ __forceinline__ unsigned short f2bf(float f) {   // RNE
  unsigned u = __float_as_uint(f);
  unsigned r = (u + 0x7FFFu + ((u >> 16) & 1u)) >> 16;
  return (unsigned short)r;
}
__device__ __forceinline__ float bf2f(unsigned short h) {
  return __uint_as_float(((unsigned)h) << 16);
}
__device__ __forceinline__ void gl2lds16(const void* g, void* l) {
  __builtin_amdgcn_global_load_lds(
      (const __attribute__((address_space(1))) void*)g,
      (__attribute__((address_space(3))) void*)l, 16, 0, 0);
}

// Prep: split W_in/W_dt/W_out/x/W_xproj(128-row zero-padded) to bf16 hi/lo
// (RNE) + zero xp. (r8: out-zero removed — GEMM4 is non-atomic now.)
__global__ __launch_bounds__(256)
void prep_kernel(const float* __restrict__ W_in, const float* __restrict__ W_dt,
                 const float* __restrict__ W_out, const float* __restrict__ x,
                 const float* __restrict__ W_xproj,
                 unsigned short* __restrict__ Whi, unsigned short* __restrict__ Wlo,
                 unsigned short* __restrict__ wdhi, unsigned short* __restrict__ wdlo,
                 unsigned short* __restrict__ Wohi, unsigned short* __restrict__ Wolo,
                 unsigned short* __restrict__ xhi, unsigned short* __restrict__ xlo,
                 unsigned short* __restrict__ wxhi, unsigned short* __restrict__ wxlo,
                 float* __restrict__ xp) {
  const int N_WIN  = 2*DI*DMODEL/4;   // 1,048,576 float4
  const int N_WDT  = DI*DTRANK/4;     //    32,768
  const int N_WOUT = DMODEL*DI/4;     //   524,288
  const int N_X    = MROWS*DMODEL/4;  // 1,048,576
  const int N_WX   = 128*DI/4;        //    65,536 (padded to 128 rows)
  const int N_XP   = MROWS*NXP/4;     //    98,304
  int i = blockIdx.x * 256 + threadIdx.x;
  const float* src = nullptr;
  unsigned short *hi = nullptr, *lo = nullptr;
  if (i < N_WIN)  { src = W_in;  hi = Whi;  lo = Wlo;  }
  else {
    i -= N_WIN;
    if (i < N_WDT)  { src = W_dt;  hi = wdhi; lo = wdlo; }
    else {
      i -= N_WDT;
      if (i < N_WOUT) { src = W_out; hi = Wohi; lo = Wolo; }
      else {
        i -= N_WOUT;
        if (i < N_X) { src = x; hi = xhi; lo = xlo; }
        else {
          i -= N_X;
          if (i < N_WX) {
            // W_xproj split, rows 96..127 zero-padded
            const int row = (i << 2) >> 11;     // /DI per-element row
            float4 v = make_float4(0.f, 0.f, 0.f, 0.f);
            if (row < NXP) v = ((const float4*)W_xproj)[i];
            ushort4 h, l;
            h.x = f2bf(v.x); h.y = f2bf(v.y); h.z = f2bf(v.z); h.w = f2bf(v.w);
            l.x = f2bf(v.x - bf2f(h.x)); l.y = f2bf(v.y - bf2f(h.y));
            l.z = f2bf(v.z - bf2f(h.z)); l.w = f2bf(v.w - bf2f(h.w));
            ((ushort4*)wxhi)[i] = h; ((ushort4*)wxlo)[i] = l;
            return;
          }
          i -= N_WX;
          if (i < N_XP) ((float4*)xp)[i] = make_float4(0.f,0.f,0.f,0.f);
          return;
        }
      }
    }
  }
  float4 v = ((const float4*)src)[i];
  ushort4 h, l;
  h.x = f2bf(v.x); h.y = f2bf(v.y); h.z = f2bf(v.z); h.w = f2bf(v.w);
  l.x = f2bf(v.x - bf2f(h.x)); l.y = f2bf(v.y - bf2f(h.y));
  l.z = f2bf(v.z - bf2f(h.z)); l.w = f2bf(v.w - bf2f(h.w));
  ((ushort4*)hi)[i] = h; ((ushort4*)lo)[i] = l;
}

// ---- Dedicated dt GEMM: dt = softplus(xp[:,0:64] @ W_dt^T + b_dt) ----
// K=64 in registers: NO LDS, NO barriers. r4-proven.
__global__ __launch_bounds__(256)
void dt_gemm_kernel(const float* __restrict__ xp_,
                    const unsigned short* __restrict__ wdhi,
                    const unsigned short* __restrict__ wdlo,
                    const float* __restrict__ bias,
                    float* __restrict__ dtb_) {
  const int tid  = threadIdx.x;
  const int lane = tid & 63;
  const int wv   = tid >> 6;
  const int wm   = wv >> 1, wn = wv & 1;
  const int quad = lane >> 4, lr = lane & 15;
  const int bm = blockIdx.y * 128, bn = blockIdx.x * 128;

  f32x4 acc[4][4];
  #pragma unroll
  for (int i = 0; i < 4; ++i)
    #pragma unroll
    for (int j = 0; j < 4; ++j)
      acc[i][j] = (f32x4){0.f, 0.f, 0.f, 0.f};

  #pragma unroll
  for (int kk = 0; kk < 2; ++kk) {
    const int k0 = kk * 32 + quad * 8;   // lane's k-octet within K=64
    bf16x8 ah[4], al[4], bh[4], bl[4];
    #pragma unroll
    for (int i = 0; i < 4; ++i) {
      const int row = bm + wm * 64 + i * 16 + lr;
      const float* ap = xp_ + (size_t)row * NXP + k0;
      const float4 v0 = *(const float4*)ap;
      const float4 v1 = *(const float4*)(ap + 4);
      const float av[8] = {v0.x, v0.y, v0.z, v0.w, v1.x, v1.y, v1.z, v1.w};
      bf16x8 h, l;
      #pragma unroll
      for (int e = 0; e < 8; ++e) {
        const float v = av[e];
        const unsigned u = __float_as_uint(v);
        const float rem = v - __uint_as_float(u & 0xFFFF0000u);
        h[e] = (short)(u >> 16);
        l[e] = (short)(__float_as_uint(rem) >> 16);
      }
      ah[i] = h; al[i] = l;
    }
    #pragma unroll
    for (int j = 0; j < 4; ++j) {
      const int col = bn + wn * 64 + j * 16 + lr;
      bh[j] = *(const bf16x8*)(wdhi + (size_t)col * DTRANK + k0);
      bl[j] = *(const bf16x8*)(wdlo + (size_t)col * DTRANK + k0);
    }
    #pragma unroll
    for (int i = 0; i < 4; ++i)
      #pragma unroll
      for (int j = 0; j < 4; ++j) {
        acc[i][j] = __builtin_amdgcn_mfma_f32_16x16x32_bf16(ah[i], bh[j], acc[i][j], 0, 0, 0);
        acc[i][j] = __builtin_amdgcn_mfma_f32_16x16x32_bf16(ah[i], bl[j], acc[i][j], 0, 0, 0);
        acc[i][j] = __builtin_amdgcn_mfma_f32_16x16x32_bf16(al[i], bh[j], acc[i][j], 0, 0, 0);
      }
  }

  #pragma unroll
  for (int i = 0; i < 4; ++i) {
    const int gr = bm + wm * 64 + i * 16 + quad * 4;
    #pragma unroll
    for (int j = 0; j < 4; ++j) {
      const int gc = bn + wn * 64 + j * 16 + lr;
      float* cp = dtb_ + (size_t)gr * DI + gc;
      const float bv = bias[gc];
      #pragma unroll
      for (int r = 0; r < 4; ++r)
        cp[(size_t)r * DI] = softplus_f(acc[i][j][r] + bv);
    }
  }
}

// ---- 128x128 bf16x3 GEMM body (cvt / APRE), 4 waves, BK=32, dbuf ----
// r2-proven schedule. Shared __device__ body; distinct __global__ wrappers.
template<bool ATOMIC, int ACT, bool APRE>
__device__ __forceinline__
void gemm_body(const float* __restrict__ A,
               const unsigned short* __restrict__ Ahi_g,
               const unsigned short* __restrict__ Alo_g,
               int lda,
               const unsigned short* __restrict__ Bhi, const unsigned short* __restrict__ Blo,
               const float* __restrict__ bias,
               float* __restrict__ C0, float* __restrict__ C1,
               int NC, int K, int klen) {
  __shared__ __align__(16) unsigned short Ah[2 * 128 * 32];
  __shared__ __align__(16) unsigned short Al[2 * 128 * 32];
  __shared__ __align__(16) unsigned short Bh[2 * 128 * 32];
  __shared__ __align__(16) unsigned short Bl[2 * 128 * 32];
  const int tid  = threadIdx.x;
  const int lane = tid & 63;
  const int wv   = tid >> 6;
  const int wm   = wv >> 1, wn = wv & 1;
  const int quad = lane >> 4, lr = lane & 15;
  const int bm = blockIdx.y * 128, bn = blockIdx.x * 128;
  const int kbeg = blockIdx.z * klen;

  int bOff[2], aOffp[2], ldsO[2];
  #pragma unroll
  for (int j = 0; j < 2; ++j) {
    const int s   = (wv * 2 + j) * 64 + lane;
    const int row = s >> 2;
    const int c   = (s & 3) ^ ((row >> 1) & 3);
    bOff[j]  = (bn + row) * K + c * 8;
    aOffp[j] = (bm + row) * lda + c * 8;
    ldsO[j]  = (wv * 2 + j) << 10;
  }
  const int ar = tid >> 1;
  const int ahalf = tid & 1;
  const int asw = (ar >> 1) & 3;
  const int aw0 = (ar * 4 + ((ahalf * 2)     ^ asw)) << 4;
  const int aw1 = (ar * 4 + ((ahalf * 2 + 1) ^ asw)) << 4;
  const float* aptr = (!APRE) ? (A + (size_t)(bm + ar) * lda + ahalf * 16) : nullptr;

  int aRd[4], bRd[4];
  #pragma unroll
  for (int i = 0; i < 4; ++i) {
    const int ra = wm * 64 + i * 16 + lr;
    aRd[i] = (ra * 4 + (quad ^ ((ra >> 1) & 3))) << 4;
    const int rb = wn * 64 + i * 16 + lr;
    bRd[i] = (rb * 4 + (quad ^ ((rb >> 1) & 3))) << 4;
  }

  f32x4 acc[4][4];
  #pragma unroll
  for (int i = 0; i < 4; ++i)
    #pragma unroll
    for (int j = 0; j < 4; ++j)
      acc[i][j] = (f32x4){0.f, 0.f, 0.f, 0.f};

  const int nt = klen / 32;
  float ac[16], an[16];

  if constexpr (APRE) {
    #pragma unroll
    for (int j = 0; j < 2; ++j) {
      gl2lds16(Bhi   + (size_t)bOff[j]  + kbeg, (char*)Bh + ldsO[j]);
      gl2lds16(Blo   + (size_t)bOff[j]  + kbeg, (char*)Bl + ldsO[j]);
      gl2lds16(Ahi_g + (size_t)aOffp[j] + kbeg, (char*)Ah + ldsO[j]);
      gl2lds16(Alo_g + (size_t)aOffp[j] + kbeg, (char*)Al + ldsO[j]);
    }
  } else {
    #pragma unroll
    for (int j = 0; j < 2; ++j) {
      gl2lds16(Bhi + (size_t)bOff[j] + kbeg, (char*)Bh + ldsO[j]);
      gl2lds16(Blo + (size_t)bOff[j] + kbeg, (char*)Bl + ldsO[j]);
    }
    #pragma unroll
    for (int q = 0; q < 4; ++q)
      *(float4*)&ac[q * 4] = *(const float4*)(aptr + kbeg + q * 4);
    u16x8 vh[2], vl[2];
    #pragma unroll
    for (int g = 0; g < 2; ++g)
      #pragma unroll
      for (int e = 0; e < 8; ++e) {
        const float v = ac[g * 8 + e];
        const unsigned u = __float_as_uint(v);
        const float rem = v - __uint_as_float(u & 0xFFFF0000u);
        vh[g][e] = (unsigned short)(u >> 16);
        vl[g][e] = (unsigned short)(__float_as_uint(rem) >> 16);
      }
    *(u16x8*)((char*)Ah + aw0) = vh[0];
    *(u16x8*)((char*)Ah + aw1) = vh[1];
    *(u16x8*)((char*)Al + aw0) = vl[0];
    *(u16x8*)((char*)Al + aw1) = vl[1];
    if (nt > 1) {
      #pragma unroll
      for (int q = 0; q < 4; ++q)
        *(float4*)&ac[q * 4] = *(const float4*)(aptr + kbeg + 32 + q * 4);
    }
  }
  asm volatile("s_waitcnt vmcnt(0)" ::: "memory");
  __syncthreads();

  int cur = 0;
  #pragma unroll 1
  for (int t = 0; t < nt; ++t) {
    const int km = kbeg + t * 32;
    if (t + 1 < nt) {
      const int nb = (cur ^ 1) * 8192;
      if constexpr (APRE) {
        #pragma unroll
        for (int j = 0; j < 2; ++j) {
          gl2lds16(Bhi   + (size_t)bOff[j]  + km + 32, (char*)Bh + nb + ldsO[j]);
          gl2lds16(Blo   + (size_t)bOff[j]  + km + 32, (char*)Bl + nb + ldsO[j]);
          gl2lds16(Ahi_g + (size_t)aOffp[j] + km + 32, (char*)Ah + nb + ldsO[j]);
          gl2lds16(Alo_g + (size_t)aOffp[j] + km + 32, (char*)Al + nb + ldsO[j]);
        }
      } else {
        #pragma unroll
        for (int j = 0; j < 2; ++j) {
          gl2lds16(Bhi + (size_t)bOff[j] + km + 32, (char*)Bh + nb + ldsO[j]);
          gl2lds16(Blo + (size_t)bOff[j] + km + 32, (char*)Bl + nb + ldsO[j]);
        }
        u16x8 vh[2], vl[2];
        #pragma unroll
        for (int g = 0; g < 2; ++g)
          #pragma unroll
          for (int e = 0; e < 8; ++e) {
            const float v = ac[g * 8 + e];
            const unsigned u = __float_as_uint(v);
            const float rem = v - __uint_as_float(u & 0xFFFF0000u);
            vh[g][e] = (unsigned short)(u >> 16);
            vl[g][e] = (unsigned short)(__float_as_uint(rem) >> 16);
          }
        *(u16x8*)((char*)Ah + nb + aw0) = vh[0];
        *(u16x8*)((char*)Ah + nb + aw1) = vh[1];
        *(u16x8*)((char*)Al + nb + aw0) = vl[0];
        *(u16x8*)((char*)Al + nb + aw1) = vl[1];
        if (t + 2 < nt) {
          #pragma unroll
          for (int q = 0; q < 4; ++q)
            *(float4*)&an[q * 4] = *(const float4*)(aptr + km + 64 + q * 4);
        }
      }
    }
    const int cb = cur * 8192;
    bf16x8 ah[4], al[4], bh[4], bl[4];
    #pragma unroll
    for (int i = 0; i < 4; ++i) {
      ah[i] = *(const bf16x8*)((const char*)Ah + cb + aRd[i]);
      al[i] = *(const bf16x8*)((const char*)Al + cb + aRd[i]);
      bh[i] = *(const bf16x8*)((const char*)Bh + cb + bRd[i]);
      bl[i] = *(const bf16x8*)((const char*)Bl + cb + bRd[i]);
    }
    #pragma unroll
    for (int i = 0; i < 4; ++i)
      #pragma unroll
      for (int j = 0; j < 4; ++j) {
        acc[i][j] = __builtin_amdgcn_mfma_f32_16x16x32_bf16(ah[i], bh[j], acc[i][j], 0, 0, 0);
        acc[i][j] = __builtin_amdgcn_mfma_f32_16x16x32_bf16(ah[i], bl[j], acc[i][j], 0, 0, 0);
        acc[i][j] = __builtin_amdgcn_mfma_f32_16x16x32_bf16(al[i], bh[j], acc[i][j], 0, 0, 0);
      }
    if (t + 1 < nt) {
      asm volatile("s_waitcnt vmcnt(0)" ::: "memory");
      __syncthreads();
      if constexpr (!APRE) {
        if (t + 2 < nt) {
          #pragma unroll
          for (int e = 0; e < 16; ++e) ac[e] = an[e];
        }
      }
      cur ^= 1;
    }
  }

  float* C = C0;
  int bnc = bn;
  if (bn >= NC) { C = C1; bnc = bn - NC; }

  #pragma unroll
  for (int i = 0; i < 4; ++i) {
    const int gr = bm + wm * 64 + i * 16 + quad * 4;
    #pragma unroll
    for (int j = 0; j < 4; ++j) {
      const int gc = bnc + wn * 64 + j * 16 + lr;
      float* cp = C + (size_t)gr * NC + gc;
      const float bv = (ACT == 1) ? bias[gc] : 0.f;
      #pragma unroll
      for (int r = 0; r < 4; ++r) {
        float v = acc[i][j][r];
        if (ACT == 1) v = softplus_f(v + bv);
        if (ATOMIC) atomicAdd(&cp[(size_t)r * NC], v);
        else        cp[(size_t)r * NC] = v;
      }
    }
  }
}

// GEMM1: [xc|z] = x @ W_in^T, A pre-split (APRE). Launched as two half-grids
// (r8 attribution split): caller offsets A planes and C pointers by row.
__global__ __launch_bounds__(256)
void gemm_in_bf16x3(const unsigned short* __restrict__ Ahi_g,
                    const unsigned short* __restrict__ Alo_g, int lda,
                    const unsigned short* __restrict__ Bhi,
                    const unsigned short* __restrict__ Blo,
                    float* __restrict__ C0, float* __restrict__ C1,
                    int NC, int K, int klen) {
  gemm_body<false, 0, true>(nullptr, Ahi_g, Alo_g, lda, Bhi, Blo, nullptr,
                            C0, C1, NC, K, klen);
}

// GEMM4 (r8): out = y @ W_out^T, A = y bf16 planes (APRE). NO split-K:
// grid (8,32) = 256 blocks = 1/CU single pass, plain stores, no atomics,
// no out pre-zero. Same template instantiation as gemm_in (rule-19-safe).
__global__ __launch_bounds__(256)
void gemm_out_bf16x3(const unsigned short* __restrict__ Ahi_g,
                     const unsigned short* __restrict__ Alo_g, int lda,
                     const unsigned short* __restrict__ Bhi,
                     const unsigned short* __restrict__ Blo,
                     float* __restrict__ C0,
                     int NC, int K, int klen) {
  gemm_body<false, 0, true>(nullptr, Ahi_g, Alo_g, lda, Bhi, Blo, nullptr,
                            C0, C0, NC, K, klen);
}

// ---- GEMM2: xp = xc2 @ W_xproj^T as MFMA bf16x3, APRE both sides ----
// r6-proven. M=4096, N=96 (tile 128x128, cols >=96 masked), K=2048 split 8.
__global__ __launch_bounds__(256)
void xproj_gemm_bf16x3(const unsigned short* __restrict__ Ahi_g,
                       const unsigned short* __restrict__ Alo_g,
                       const unsigned short* __restrict__ Bhi,
                       const unsigned short* __restrict__ Blo,
                       float* __restrict__ C, int klen) {
  __shared__ __align__(16) unsigned short Ah[2 * 128 * 32];
  __shared__ __align__(16) unsigned short Al[2 * 128 * 32];
  __shared__ __align__(16) unsigned short Bh[2 * 128 * 32];
  __shared__ __align__(16) unsigned short Bl[2 * 128 * 32];
  const int tid  = threadIdx.x;
  const int lane = tid & 63;
  const int wv   = tid >> 6;
  const int wm   = wv >> 1, wn = wv & 1;
  const int quad = lane >> 4, lr = lane & 15;
  const int bm = blockIdx.y * 128;
  const int kbeg = blockIdx.z * klen;

  int bOff[2], aOff[2], ldsO[2];
  #pragma unroll
  for (int j = 0; j < 2; ++j) {
    const int s   = (wv * 2 + j) * 64 + lane;
    const int row = s >> 2;
    const int c   = (s & 3) ^ ((row >> 1) & 3);
    bOff[j] = row * DI + c * 8;            // padded 128-row B, stride DI
    aOff[j] = (bm + row) * DI + c * 8;
    ldsO[j] = (wv * 2 + j) << 10;
  }
  int aRd[4], bRd[4];
  #pragma unroll
  for (int i = 0; i < 4; ++i) {
    const int ra = wm * 64 + i * 16 + lr;
    aRd[i] = (ra * 4 + (quad ^ ((ra >> 1) & 3))) << 4;
    const int rb = wn * 64 + i * 16 + lr;
    bRd[i] = (rb * 4 + (quad ^ ((rb >> 1) & 3))) << 4;
  }

  f32x4 acc[4][4];
  #pragma unroll
  for (int i = 0; i < 4; ++i)
    #pragma unroll
    for (int j = 0; j < 4; ++j)
      acc[i][j] = (f32x4){0.f, 0.f, 0.f, 0.f};

  const int nt = klen / 32;
  #pragma unroll
  for (int j = 0; j < 2; ++j) {
    gl2lds16(Ahi_g + (size_t)aOff[j] + kbeg, (char*)Ah + ldsO[j]);
    gl2lds16(Alo_g + (size_t)aOff[j] + kbeg, (char*)Al + ldsO[j]);
    gl2lds16(Bhi   + (size_t)bOff[j] + kbeg, (char*)Bh + ldsO[j]);
    gl2lds16(Blo   + (size_t)bOff[j] + kbeg, (char*)Bl + ldsO[j]);
  }
  asm volatile("s_waitcnt vmcnt(0)" ::: "memory");
  __syncthreads();

  int cur = 0;
  #pragma unroll 1
  for (int t = 0; t < nt; ++t) {
    const int km = kbeg + t * 32;
    if (t + 1 < nt) {
      const int nb = (cur ^ 1) * 8192;
      #pragma unroll
      for (int j = 0; j < 2; ++j) {
        gl2lds16(Ahi_g + (size_t)aOff[j] + km + 32, (char*)Ah + nb + ldsO[j]);
        gl2lds16(Alo_g + (size_t)aOff[j] + km + 32, (char*)Al + nb + ldsO[j]);
        gl2lds16(Bhi   + (size_t)bOff[j] + km + 32, (char*)Bh + nb + ldsO[j]);
        gl2lds16(Blo   + (size_t)bOff[j] + km + 32, (char*)Bl + nb + ldsO[j]);
      }
    }
    const int cb = cur * 8192;
    bf16x8 ah[4], al[4], bh[4], bl[4];
    #pragma unroll
    for (int i = 0; i < 4; ++i) {
      ah[i] = *(const bf16x8*)((const char*)Ah + cb + aRd[i]);
      al[i] = *(const bf16x8*)((const char*)Al + cb + aRd[i]);
      bh[i] = *(const bf16x8*)((const char*)Bh + cb + bRd[i]);
      bl[i] = *(const bf16x8*)((const char*)Bl + cb + bRd[i]);
    }
    #pragma unroll
    for (int i = 0; i < 4; ++i)
      #pragma unroll
      for (int j = 0; j < 4; ++j) {
        acc[i][j] = __builtin_amdgcn_mfma_f32_16x16x32_bf16(ah[i], bh[j], acc[i][j], 0, 0, 0);
        acc[i][j] = __builtin_amdgcn_mfma_f32_16x16x32_bf16(ah[i], bl[j], acc[i][j], 0, 0, 0);
        acc[i][j] = __builtin_amdgcn_mfma_f32_16x16x32_bf16(al[i], bh[j], acc[i][j], 0, 0, 0);
      }
    if (t + 1 < nt) {
      asm volatile("s_waitcnt vmcnt(0)" ::: "memory");
      __syncthreads();
      cur ^= 1;
    }
  }

  #pragma unroll
  for (int i = 0; i < 4; ++i) {
    const int gr = bm + wm * 64 + i * 16 + quad * 4;
    #pragma unroll
    for (int j = 0; j < 4; ++j) {
      const int gc = wn * 64 + j * 16 + lr;
      if (gc < NXP) {
        float* cp = C + (size_t)gr * NXP + gc;
        #pragma unroll
        for (int r = 0; r < 4; ++r)
          atomicAdd(&cp[(size_t)r * NXP], acc[i][j][r]);
      }
    }
  }
}

// Causal depthwise conv (width 4) + bias + SiLU.
// thread = 4 consecutive d (float4), one l; also emits bf16 hi/lo planes.
__global__ __launch_bounds__(256)
void conv_silu_kernel(const float* __restrict__ xc_raw, const float* __restrict__ cw,
                      const float* __restrict__ cb, float* __restrict__ xc2,
                      unsigned short* __restrict__ xc2hi,
                      unsigned short* __restrict__ xc2lo) {
  const int tid = blockIdx.x * 256 + threadIdx.x;   // NB*LSEQ*(DI/4) threads
  const int d4 = tid & (DI / 4 - 1);                // d-group (4 floats)
  const int l  = (tid >> 9) & (LSEQ - 1);
  const int b  = tid >> 20;
  const size_t rowb = ((size_t)b * LSEQ + l) * DI + d4 * 4;
  float4 xj[4];
  #pragma unroll
  for (int j = 0; j < 4; ++j) {
    const int ls = l - 3 + j;
    xj[j] = (ls >= 0) ? *(const float4*)(xc_raw + rowb + ((long long)j - 3) * DI)
                      : make_float4(0.f, 0.f, 0.f, 0.f);
  }
  const float4 bias = *(const float4*)(cb + d4 * 4);
  float o[4];
  #pragma unroll
  for (int k = 0; k < 4; ++k) {
    const float4 w = *(const float4*)(cw + (d4 * 4 + k) * 4);
    const float xv[4] = { ((const float*)&xj[0])[k], ((const float*)&xj[1])[k],
                          ((const float*)&xj[2])[k], ((const float*)&xj[3])[k] };
    float acc = fmaf(w.x, xv[0], ((const float*)&bias)[k]);
    acc = fmaf(w.y, xv[1], acc);
    acc = fmaf(w.z, xv[2], acc);
    acc = fmaf(w.w, xv[3], acc);
    o[k] = silu_f(acc);
  }
  *(float4*)(xc2 + rowb) = make_float4(o[0], o[1], o[2], o[3]);
  ushort4 h, lo4;
  h.x = f2bf(o[0]); h.y = f2bf(o[1]); h.z = f2bf(o[2]); h.w = f2bf(o[3]);
  lo4.x = f2bf(o[0] - bf2f(h.x)); lo4.y = f2bf(o[1] - bf2f(h.y));
  lo4.z = f2bf(o[2] - bf2f(h.z)); lo4.w = f2bf(o[3] - bf2f(h.w));
  *(ushort4*)(xc2hi + rowb) = h;
  *(ushort4*)(xc2lo + rowb) = lo4;
}

// ---- Pass 1 (lite): per-chunk summaries ONLY ----
__global__ __launch_bounds__(256)
void scan_chunk_kernel(const float* __restrict__ xc2, const float* __restrict__ dtb,
                       const float* __restrict__ xp, const float* __restrict__ A_log,
                       float* __restrict__ hloc, float* __restrict__ totdt) {
  __shared__ float sB[LC][DSTATE];   // 4 KB
  const int d = blockIdx.x * 256 + threadIdx.x;
  const int b = blockIdx.y;
  const int c = blockIdx.z;

  float A[DSTATE], h[DSTATE];
  #pragma unroll
  for (int n = 0; n < DSTATE; ++n) {
    A[n] = -__expf(A_log[(size_t)d * DSTATE + n]);
    h[n] = 0.f;
  }

  {
    const float* xpb = xp + ((size_t)b * LSEQ + (size_t)c * LC) * NXP + DTRANK;
    const int row = threadIdx.x >> 2, q = threadIdx.x & 3;
    *(float4*)&sB[row][q * 4] = *(const float4*)&xpb[(size_t)row * NXP + q * 4];
  }
  __syncthreads();

  const size_t cbase = ((size_t)b * LSEQ + (size_t)c * LC) * DI + d;
  float cum = 0.f;
  constexpr int U = 4;
  float cdt[U], cx[U];
  #pragma unroll
  for (int u = 0; u < U; ++u) {
    cdt[u] = dtb[cbase + (size_t)u * DI];
    cx[u]  = xc2[cbase + (size_t)u * DI];
  }

  #pragma unroll 1
  for (int g = 0; g < LC; g += U) {
    float ndt[U], nx[U];
    if (g + U < LC) {
      #pragma unroll
      for (int u = 0; u < U; ++u) {
        ndt[u] = dtb[cbase + (size_t)(g + U + u) * DI];
        nx[u]  = xc2[cbase + (size_t)(g + U + u) * DI];
      }
    }
    #pragma unroll
    for (int u = 0; u < U; ++u) {
      const int t = g + u;
      const float dt = cdt[u];
      const float dx = dt * cx[u];
      cum += dt;
      #pragma unroll
      for (int n = 0; n < DSTATE; ++n) {
        const float ab = __expf(dt * A[n]);
        h[n] = fmaf(ab, h[n], dx * sB[t][n]);
      }
    }
    if (g + U < LC) {
      #pragma unroll
      for (int u = 0; u < U; ++u) { cdt[u] = ndt[u]; cx[u] = nx[u]; }
    }
  }

  const size_t hbase = ((size_t)(b * CHUNKS + c)) * DSTATE * DI + d;
  #pragma unroll
  for (int n = 0; n < DSTATE; ++n) hloc[hbase + (size_t)n * DI] = h[n];
  totdt[((size_t)(b * CHUNKS + c)) * DI + d] = cum;
}

// Pass 2: carry propagation (in-place local-end -> carry-in). Unchanged.
__global__ __launch_bounds__(256)
void scan_carry_kernel(float* __restrict__ hloc, const float* __restrict__ totdt,
                       const float* __restrict__ A_log) {
  const int tid = blockIdx.x * 256 + threadIdx.x;   // NB*DSTATE*DI
  const int d = tid & (DI - 1);
  const int n = (tid >> 11) & 15;
  const int b = tid >> 15;
  const float An = -__expf(A_log[(size_t)d * DSTATE + n]);
  float h = 0.f;
  float le = hloc[((size_t)(b * CHUNKS) * DSTATE + n) * DI + d];
  float td = totdt[(size_t)(b * CHUNKS) * DI + d];
  for (int c = 0; c < CHUNKS; ++c) {
    const size_t ix = ((size_t)(b * CHUNKS + c) * DSTATE + n) * DI + d;
    float nle = 0.f, ntd = 0.f;
    if (c + 1 < CHUNKS) {
      nle = hloc[ix + (size_t)DSTATE * DI];
      ntd = totdt[(size_t)(b * CHUNKS + c + 1) * DI + d];
    }
    hloc[ix] = h;
    h = fmaf(__expf(An * td), h, le);
    le = nle; td = ntd;
  }
}

// ---- Pass 3: direct recurrence from carry-in; emit y as bf16 hi/lo ----
__global__ __launch_bounds__(256)
void scan_final_kernel(const float* __restrict__ xc2, const float* __restrict__ dtb,
                       const float* __restrict__ xp, const float* __restrict__ zbuf,
                       const float* __restrict__ A_log, const float* __restrict__ Dp,
                       const float* __restrict__ hloc,
                       unsigned short* __restrict__ yhi,
                       unsigned short* __restrict__ ylo) {
  __shared__ float sbc[LC][32];   // 8 KB: [t][0:16)=B, [16:32)=C
  const int tid = threadIdx.x;
  const int d = blockIdx.x * 256 + tid;
  const int b = blockIdx.y;
  const int c = blockIdx.z;

  float A[DSTATE], h[DSTATE];
  {
    const float* hp = hloc + ((size_t)(b * CHUNKS + c)) * DSTATE * DI + d;
    const float* ap = A_log + (size_t)d * DSTATE;
    #pragma unroll
    for (int n = 0; n < DSTATE; ++n) {
      A[n] = -__expf(ap[n]);
      h[n] = hp[(size_t)n * DI];     // carry-in state
    }
  }
  {
    const float* xpb = xp + ((size_t)b * LSEQ + (size_t)c * LC) * NXP + DTRANK;
    #pragma unroll
    for (int kk = 0; kk < 2; ++kk) {
      const int slot = tid + kk * 256;
      const int row = slot >> 3, q4 = (slot & 7) << 2;
      *(float4*)&sbc[row][q4] = *(const float4*)&xpb[(size_t)row * NXP + q4];
    }
  }
  __syncthreads();

  const float Dd = Dp[d];
  const size_t cbase = ((size_t)b * LSEQ + (size_t)c * LC) * DI + d;
  constexpr int U = 4;
  float cdt[U], cx[U], cz[U];
  #pragma unroll
  for (int u = 0; u < U; ++u) {
    cdt[u] = dtb[cbase + (size_t)u * DI];
    cx[u]  = xc2[cbase + (size_t)u * DI];
    cz[u]  = zbuf[cbase + (size_t)u * DI];
  }

  #pragma unroll 1
  for (int g = 0; g < LC; g += U) {
    float ndt[U], nx[U], nz[U];
    if (g + U < LC) {
      #pragma unroll
      for (int u = 0; u < U; ++u) {
        ndt[u] = dtb[cbase + (size_t)(g + U + u) * DI];
        nx[u]  = xc2[cbase + (size_t)(g + U + u) * DI];
        nz[u]  = zbuf[cbase + (size_t)(g + U + u) * DI];
      }
    }
    #pragma unroll
    for (int u = 0; u < U; ++u) {
      const int t = g + u;
      const float dt = cdt[u];
      const float dx = dt * cx[u];
      #pragma unroll
      for (int n = 0; n < DSTATE; ++n) {
        const float ab = __expf(dt * A[n]);
        h[n] = fmaf(ab, h[n], dx * sbc[t][n]);
      }
      float p[DSTATE];
      #pragma unroll
      for (int n = 0; n < DSTATE; ++n) p[n] = h[n] * sbc[t][DSTATE + n];
      #pragma unroll
      for (int s = 1; s < DSTATE; s <<= 1)
        #pragma unroll
        for (int n = 0; n < DSTATE; n += 2 * s) p[n] += p[n + s];
      const float yv = (p[0] + cx[u] * Dd) * silu_f(cz[u]);
      const size_t base = cbase + (size_t)t * DI;
      const unsigned short hh = f2bf(yv);
      yhi[base] = hh;
      ylo[base] = f2bf(yv - bf2f(hh));
    }
    if (g + U < LC) {
      #pragma unroll
      for (int u = 0; u < U; ++u) { cdt[u] = ndt[u]; cx[u] = nx[u]; cz[u] = nz[u]; }
    }
  }
}

extern "C" void kernel_launch(void* const* d_in, const int* in_sizes, int n_in,
                              void* d_out, int out_size, void* d_ws, size_t ws_size,
                              hipStream_t stream) {
  const float* x      = (const float*)d_in[0];
  const float* W_in   = (const float*)d_in[1];
  const float* conv_w = (const float*)d_in[2];
  const float* conv_b = (const float*)d_in[3];
  const float* W_xproj= (const float*)d_in[4];
  const float* W_dt   = (const float*)d_in[5];
  const float* b_dt   = (const float*)d_in[6];
  const float* A_log  = (const float*)d_in[7];
  const float* Dp     = (const float*)d_in[8];
  const float* W_out  = (const float*)d_in[9];
  float* out = (float*)d_out;
  float* ws  = (float*)d_ws;

  // ws layout (floats), ~154 MB:
  //   xc_raw[SEG] | zbuf[SEG] | xc2[SEG] | dtb[SEG] | xp | hloc | totdt | pools
  // Overlays (time-disjoint):
  //   Whi/Wlo over dtb        — consumed by GEMM1 (dtb written later by dt_gemm).
  //   xc2hi/xc2lo over dtb    — conv..xproj window, dead before dt_gemm.
  //   xhi/xlo over xc2        — prep..GEMM1 window; conv overwrites xc2.
  //   yhi/ylo over xc_raw     — scan_final output, consumed by GEMM4 APRE.
  const size_t SEG = (size_t)NB * LSEQ * DI;            // 8,388,608
  float* xc_raw = ws;
  float* zbuf   = ws + SEG;
  float* xc2    = ws + 2 * SEG;
  float* dtb    = ws + 3 * SEG;
  float* xp     = ws + 4 * SEG;                         // 393,216
  float* hloc   = xp + (size_t)MROWS * NXP;             // 2,097,152
  float* totdt  = hloc + (size_t)NB * CHUNKS * DSTATE * DI;  // 131,072
  float* wpool  = totdt + (size_t)NB * CHUNKS * DI;

  unsigned short* Whi = (unsigned short*)dtb;           // overlay (dead before conv)
  unsigned short* Wlo = Whi + (size_t)2 * DI * DMODEL;

  unsigned short* xc2hi = (unsigned short*)dtb;         // overlay (conv..xproj window)
  unsigned short* xc2lo = xc2hi + (size_t)MROWS * DI;

  unsigned short* xhi = (unsigned short*)xc2;           // overlay (dead until conv)
  unsigned short* xlo = xhi + (size_t)MROWS * DMODEL;

  unsigned short* yhi = (unsigned short*)xc_raw;        // overlay (scan_final..GEMM4)
  unsigned short* ylo = yhi + (size_t)MROWS * DI;

  unsigned short* Wohi = (unsigned short*)wpool;        // 2,097,152 ushort
  unsigned short* Wolo = Wohi + (size_t)DMODEL * DI;
  unsigned short* wdhi = Wolo + (size_t)DMODEL * DI;    // 131,072 ushort
  unsigned short* wdlo = wdhi + (size_t)DI * DTRANK;
  unsigned short* wxhi = wdlo + (size_t)DI * DTRANK;    // 262,144 ushort (padded 128xDI)
  unsigned short* wxlo = wxhi + (size_t)128 * DI;

  dim3 blk(256);

  // Prep: weight + x splits (incl. padded W_xproj), zero xp (no out-zero)
  const int prep_blocks = (2*DI*DMODEL/4 + DI*DTRANK/4 + DMODEL*DI/4
                           + MROWS*DMODEL/4 + 128*DI/4 + MROWS*NXP/4) / 256;
  prep_kernel<<<prep_blocks, blk, 0, stream>>>(
      W_in, W_dt, W_out, x, W_xproj, Whi, Wlo, wdhi, wdlo, Wohi, Wolo,
      xhi, xlo, wxhi, wxlo, xp);

  // GEMM1 fused: [xc | z] = x @ W_in^T  (128^2, A pre-split; K=1024)
  // r8: two half-grid launches (rows 0..2047 / 2048..4095) for rocprof
  // attribution — offset A planes and C pointers; body unchanged.
  const size_t rowHalf = (size_t)(MROWS / 2);
  gemm_in_bf16x3<<<dim3(2*DI/128, MROWS/256, 1), blk, 0, stream>>>(
      xhi, xlo, DMODEL, Whi, Wlo, xc_raw, zbuf, DI, DMODEL, DMODEL);
  gemm_in_bf16x3<<<dim3(2*DI/128, MROWS/256, 1), blk, 0, stream>>>(
      xhi + rowHalf * DMODEL, xlo + rowHalf * DMODEL, DMODEL, Whi, Wlo,
      xc_raw + rowHalf * DI, zbuf + rowHalf * DI, DI, DMODEL, DMODEL);

  // conv + bias + SiLU (float4 over d) + bf16 hi/lo planes of xc2
  conv_silu_kernel<<<(NB*LSEQ*(DI/4))/256, blk, 0, stream>>>(
      xc_raw, conv_w, conv_b, xc2, xc2hi, xc2lo);

  // GEMM2: xp = xc2 @ W_xproj^T — MFMA bf16x3, split-K=8 atomic (xp zeroed)
  xproj_gemm_bf16x3<<<dim3(1, MROWS/128, 8), blk, 0, stream>>>(
      xc2hi, xc2lo, wxhi, wxlo, xp, DI/8);

  // GEMM3: dt = softplus(dt_lr @ W_dt^T + b_dt) — dedicated LDS-free kernel
  dt_gemm_kernel<<<dim3(DI/128, MROWS/128, 1), blk, 0, stream>>>(
      xp, wdhi, wdlo, b_dt, dtb);

  // Scan: summaries -> carries -> direct recurrence emitting y bf16 planes
  scan_chunk_kernel<<<dim3(DI/256, NB, CHUNKS), blk, 0, stream>>>(
      xc2, dtb, xp, A_log, hloc, totdt);
  scan_carry_kernel<<<(NB*DI*DSTATE)/256, blk, 0, stream>>>(hloc, totdt, A_log);
  scan_final_kernel<<<dim3(DI/256, NB, CHUNKS), blk, 0, stream>>>(
      xc2, dtb, xp, zbuf, A_log, Dp, hloc, yhi, ylo);

  // GEMM4: out = y @ W_out^T — A = y bf16 planes (APRE), NO split-K,
  // plain stores (no atomics, no pre-zero). Grid 256 = 1 block/CU.
  gemm_out_bf16x3<<<dim3(DMODEL/128, MROWS/128, 1), blk, 0, stream>>>(
      yhi, ylo, DI, Wohi, Wolo, out, DMODEL, DI, DI);
}

// Round 10
// 425.099 us; speedup vs baseline: 1.0501x; 1.0501x over previous
//
#include <hip/hip_runtime.h>
#include <cstddef>
#include <cstdint>

// Problem constants (match reference)
#define DMODEL 1024
#define DI     2048      // D_INNER
#define LSEQ   2048
#define NB     2
#define DSTATE 16
#define DTRANK 64
#define NXP    96        // DT_RANK + 2*D_STATE
#define MROWS  (NB*LSEQ) // 4096 GEMM rows
#define CHUNKS 32
#define LC     (LSEQ/CHUNKS)   // 64

typedef __attribute__((ext_vector_type(8))) short bf16x8;
typedef __attribute__((ext_vector_type(8))) unsigned short u16x8;
typedef __attribute__((ext_vector_type(4))) float f32x4;

__device__ __forceinline__ float silu_f(float v) {
  return v / (1.f + __expf(-v));
}
__device__ __forceinline__ float softplus_f(float v) {
  return (v > 20.f) ? v : log1pf(__expf(v));
}
__device__ __forceinline__ unsigned short f2bf(float f) {   // RNE
  unsigned u = __float_as_uint(f);
  unsigned r = (u + 0x7FFFu + ((u >> 16) & 1u)) >> 16;
  return (unsigned short)r;
}
__device__ __forceinline__ float bf2f(unsigned short h) {
  return __uint_as_float(((unsigned)h) << 16);
}
__device__ __forceinline__ void gl2lds16(const void* g, void* l) {
  __builtin_amdgcn_global_load_lds(
      (const __attribute__((address_space(1))) void*)g,
      (__attribute__((address_space(3))) void*)l, 16, 0, 0);
}

// Prep: split W_in/W_dt/W_out/x/W_xproj(128-row zero-padded) to bf16 hi/lo
// (RNE) + zero xp and out (r10: out-zero restored — GEMM4 atomic again).
__global__ __launch_bounds__(256)
void prep_kernel(const float* __restrict__ W_in, const float* __restrict__ W_dt,
                 const float* __restrict__ W_out, const float* __restrict__ x,
                 const float* __restrict__ W_xproj,
                 unsigned short* __restrict__ Whi, unsigned short* __restrict__ Wlo,
                 unsigned short* __restrict__ wdhi, unsigned short* __restrict__ wdlo,
                 unsigned short* __restrict__ Wohi, unsigned short* __restrict__ Wolo,
                 unsigned short* __restrict__ xhi, unsigned short* __restrict__ xlo,
                 unsigned short* __restrict__ wxhi, unsigned short* __restrict__ wxlo,
                 float* __restrict__ xp, float* __restrict__ out) {
  const int N_WIN  = 2*DI*DMODEL/4;   // 1,048,576 float4
  const int N_WDT  = DI*DTRANK/4;     //    32,768
  const int N_WOUT = DMODEL*DI/4;     //   524,288
  const int N_X    = MROWS*DMODEL/4;  // 1,048,576
  const int N_WX   = 128*DI/4;        //    65,536 (padded to 128 rows)
  const int N_XP   = MROWS*NXP/4;     //    98,304
  const int N_OUT  = MROWS*DMODEL/4;  // 1,048,576
  int i = blockIdx.x * 256 + threadIdx.x;
  const float* src = nullptr;
  unsigned short *hi = nullptr, *lo = nullptr;
  if (i < N_WIN)  { src = W_in;  hi = Whi;  lo = Wlo;  }
  else {
    i -= N_WIN;
    if (i < N_WDT)  { src = W_dt;  hi = wdhi; lo = wdlo; }
    else {
      i -= N_WDT;
      if (i < N_WOUT) { src = W_out; hi = Wohi; lo = Wolo; }
      else {
        i -= N_WOUT;
        if (i < N_X) { src = x; hi = xhi; lo = xlo; }
        else {
          i -= N_X;
          if (i < N_WX) {
            // W_xproj split, rows 96..127 zero-padded
            const int row = (i << 2) >> 11;     // /DI per-element row
            float4 v = make_float4(0.f, 0.f, 0.f, 0.f);
            if (row < NXP) v = ((const float4*)W_xproj)[i];
            ushort4 h, l;
            h.x = f2bf(v.x); h.y = f2bf(v.y); h.z = f2bf(v.z); h.w = f2bf(v.w);
            l.x = f2bf(v.x - bf2f(h.x)); l.y = f2bf(v.y - bf2f(h.y));
            l.z = f2bf(v.z - bf2f(h.z)); l.w = f2bf(v.w - bf2f(h.w));
            ((ushort4*)wxhi)[i] = h; ((ushort4*)wxlo)[i] = l;
            return;
          }
          i -= N_WX;
          if (i < N_XP) { ((float4*)xp)[i] = make_float4(0.f,0.f,0.f,0.f); }
          else {
            i -= N_XP;
            if (i < N_OUT) ((float4*)out)[i] = make_float4(0.f,0.f,0.f,0.f);
          }
          return;
        }
      }
    }
  }
  float4 v = ((const float4*)src)[i];
  ushort4 h, l;
  h.x = f2bf(v.x); h.y = f2bf(v.y); h.z = f2bf(v.z); h.w = f2bf(v.w);
  l.x = f2bf(v.x - bf2f(h.x)); l.y = f2bf(v.y - bf2f(h.y));
  l.z = f2bf(v.z - bf2f(h.z)); l.w = f2bf(v.w - bf2f(h.w));
  ((ushort4*)hi)[i] = h; ((ushort4*)lo)[i] = l;
}

// ---- Dedicated dt GEMM: dt = softplus(xp[:,0:64] @ W_dt^T + b_dt) ----
// K=64 in registers: NO LDS, NO barriers. r4-proven.
__global__ __launch_bounds__(256)
void dt_gemm_kernel(const float* __restrict__ xp_,
                    const unsigned short* __restrict__ wdhi,
                    const unsigned short* __restrict__ wdlo,
                    const float* __restrict__ bias,
                    float* __restrict__ dtb_) {
  const int tid  = threadIdx.x;
  const int lane = tid & 63;
  const int wv   = tid >> 6;
  const int wm   = wv >> 1, wn = wv & 1;
  const int quad = lane >> 4, lr = lane & 15;
  const int bm = blockIdx.y * 128, bn = blockIdx.x * 128;

  f32x4 acc[4][4];
  #pragma unroll
  for (int i = 0; i < 4; ++i)
    #pragma unroll
    for (int j = 0; j < 4; ++j)
      acc[i][j] = (f32x4){0.f, 0.f, 0.f, 0.f};

  #pragma unroll
  for (int kk = 0; kk < 2; ++kk) {
    const int k0 = kk * 32 + quad * 8;   // lane's k-octet within K=64
    bf16x8 ah[4], al[4], bh[4], bl[4];
    #pragma unroll
    for (int i = 0; i < 4; ++i) {
      const int row = bm + wm * 64 + i * 16 + lr;
      const float* ap = xp_ + (size_t)row * NXP + k0;
      const float4 v0 = *(const float4*)ap;
      const float4 v1 = *(const float4*)(ap + 4);
      const float av[8] = {v0.x, v0.y, v0.z, v0.w, v1.x, v1.y, v1.z, v1.w};
      bf16x8 h, l;
      #pragma unroll
      for (int e = 0; e < 8; ++e) {
        const float v = av[e];
        const unsigned u = __float_as_uint(v);
        const float rem = v - __uint_as_float(u & 0xFFFF0000u);
        h[e] = (short)(u >> 16);
        l[e] = (short)(__float_as_uint(rem) >> 16);
      }
      ah[i] = h; al[i] = l;
    }
    #pragma unroll
    for (int j = 0; j < 4; ++j) {
      const int col = bn + wn * 64 + j * 16 + lr;
      bh[j] = *(const bf16x8*)(wdhi + (size_t)col * DTRANK + k0);
      bl[j] = *(const bf16x8*)(wdlo + (size_t)col * DTRANK + k0);
    }
    #pragma unroll
    for (int i = 0; i < 4; ++i)
      #pragma unroll
      for (int j = 0; j < 4; ++j) {
        acc[i][j] = __builtin_amdgcn_mfma_f32_16x16x32_bf16(ah[i], bh[j], acc[i][j], 0, 0, 0);
        acc[i][j] = __builtin_amdgcn_mfma_f32_16x16x32_bf16(ah[i], bl[j], acc[i][j], 0, 0, 0);
        acc[i][j] = __builtin_amdgcn_mfma_f32_16x16x32_bf16(al[i], bh[j], acc[i][j], 0, 0, 0);
      }
  }

  #pragma unroll
  for (int i = 0; i < 4; ++i) {
    const int gr = bm + wm * 64 + i * 16 + quad * 4;
    #pragma unroll
    for (int j = 0; j < 4; ++j) {
      const int gc = bn + wn * 64 + j * 16 + lr;
      float* cp = dtb_ + (size_t)gr * DI + gc;
      const float bv = bias[gc];
      #pragma unroll
      for (int r = 0; r < 4; ++r)
        cp[(size_t)r * DI] = softplus_f(acc[i][j][r] + bv);
    }
  }
}

// ---- 128x128 bf16x3 GEMM body (cvt / APRE), 4 waves, BK=32, dbuf ----
// r2-proven schedule. Shared __device__ body; distinct __global__ wrappers.
template<bool ATOMIC, int ACT, bool APRE>
__device__ __forceinline__
void gemm_body(const float* __restrict__ A,
               const unsigned short* __restrict__ Ahi_g,
               const unsigned short* __restrict__ Alo_g,
               int lda,
               const unsigned short* __restrict__ Bhi, const unsigned short* __restrict__ Blo,
               const float* __restrict__ bias,
               float* __restrict__ C0, float* __restrict__ C1,
               int NC, int K, int klen) {
  __shared__ __align__(16) unsigned short Ah[2 * 128 * 32];
  __shared__ __align__(16) unsigned short Al[2 * 128 * 32];
  __shared__ __align__(16) unsigned short Bh[2 * 128 * 32];
  __shared__ __align__(16) unsigned short Bl[2 * 128 * 32];
  const int tid  = threadIdx.x;
  const int lane = tid & 63;
  const int wv   = tid >> 6;
  const int wm   = wv >> 1, wn = wv & 1;
  const int quad = lane >> 4, lr = lane & 15;
  const int bm = blockIdx.y * 128, bn = blockIdx.x * 128;
  const int kbeg = blockIdx.z * klen;

  int bOff[2], aOffp[2], ldsO[2];
  #pragma unroll
  for (int j = 0; j < 2; ++j) {
    const int s   = (wv * 2 + j) * 64 + lane;
    const int row = s >> 2;
    const int c   = (s & 3) ^ ((row >> 1) & 3);
    bOff[j]  = (bn + row) * K + c * 8;
    aOffp[j] = (bm + row) * lda + c * 8;
    ldsO[j]  = (wv * 2 + j) << 10;
  }
  const int ar = tid >> 1;
  const int ahalf = tid & 1;
  const int asw = (ar >> 1) & 3;
  const int aw0 = (ar * 4 + ((ahalf * 2)     ^ asw)) << 4;
  const int aw1 = (ar * 4 + ((ahalf * 2 + 1) ^ asw)) << 4;
  const float* aptr = (!APRE) ? (A + (size_t)(bm + ar) * lda + ahalf * 16) : nullptr;

  int aRd[4], bRd[4];
  #pragma unroll
  for (int i = 0; i < 4; ++i) {
    const int ra = wm * 64 + i * 16 + lr;
    aRd[i] = (ra * 4 + (quad ^ ((ra >> 1) & 3))) << 4;
    const int rb = wn * 64 + i * 16 + lr;
    bRd[i] = (rb * 4 + (quad ^ ((rb >> 1) & 3))) << 4;
  }

  f32x4 acc[4][4];
  #pragma unroll
  for (int i = 0; i < 4; ++i)
    #pragma unroll
    for (int j = 0; j < 4; ++j)
      acc[i][j] = (f32x4){0.f, 0.f, 0.f, 0.f};

  const int nt = klen / 32;
  float ac[16], an[16];

  if constexpr (APRE) {
    #pragma unroll
    for (int j = 0; j < 2; ++j) {
      gl2lds16(Bhi   + (size_t)bOff[j]  + kbeg, (char*)Bh + ldsO[j]);
      gl2lds16(Blo   + (size_t)bOff[j]  + kbeg, (char*)Bl + ldsO[j]);
      gl2lds16(Ahi_g + (size_t)aOffp[j] + kbeg, (char*)Ah + ldsO[j]);
      gl2lds16(Alo_g + (size_t)aOffp[j] + kbeg, (char*)Al + ldsO[j]);
    }
  } else {
    #pragma unroll
    for (int j = 0; j < 2; ++j) {
      gl2lds16(Bhi + (size_t)bOff[j] + kbeg, (char*)Bh + ldsO[j]);
      gl2lds16(Blo + (size_t)bOff[j] + kbeg, (char*)Bl + ldsO[j]);
    }
    #pragma unroll
    for (int q = 0; q < 4; ++q)
      *(float4*)&ac[q * 4] = *(const float4*)(aptr + kbeg + q * 4);
    u16x8 vh[2], vl[2];
    #pragma unroll
    for (int g = 0; g < 2; ++g)
      #pragma unroll
      for (int e = 0; e < 8; ++e) {
        const float v = ac[g * 8 + e];
        const unsigned u = __float_as_uint(v);
        const float rem = v - __uint_as_float(u & 0xFFFF0000u);
        vh[g][e] = (unsigned short)(u >> 16);
        vl[g][e] = (unsigned short)(__float_as_uint(rem) >> 16);
      }
    *(u16x8*)((char*)Ah + aw0) = vh[0];
    *(u16x8*)((char*)Ah + aw1) = vh[1];
    *(u16x8*)((char*)Al + aw0) = vl[0];
    *(u16x8*)((char*)Al + aw1) = vl[1];
    if (nt > 1) {
      #pragma unroll
      for (int q = 0; q < 4; ++q)
        *(float4*)&ac[q * 4] = *(const float4*)(aptr + kbeg + 32 + q * 4);
    }
  }
  asm volatile("s_waitcnt vmcnt(0)" ::: "memory");
  __syncthreads();

  int cur = 0;
  #pragma unroll 1
  for (int t = 0; t < nt; ++t) {
    const int km = kbeg + t * 32;
    if (t + 1 < nt) {
      const int nb = (cur ^ 1) * 8192;
      if constexpr (APRE) {
        #pragma unroll
        for (int j = 0; j < 2; ++j) {
          gl2lds16(Bhi   + (size_t)bOff[j]  + km + 32, (char*)Bh + nb + ldsO[j]);
          gl2lds16(Blo   + (size_t)bOff[j]  + km + 32, (char*)Bl + nb + ldsO[j]);
          gl2lds16(Ahi_g + (size_t)aOffp[j] + km + 32, (char*)Ah + nb + ldsO[j]);
          gl2lds16(Alo_g + (size_t)aOffp[j] + km + 32, (char*)Al + nb + ldsO[j]);
        }
      } else {
        #pragma unroll
        for (int j = 0; j < 2; ++j) {
          gl2lds16(Bhi + (size_t)bOff[j] + km + 32, (char*)Bh + nb + ldsO[j]);
          gl2lds16(Blo + (size_t)bOff[j] + km + 32, (char*)Bl + nb + ldsO[j]);
        }
        u16x8 vh[2], vl[2];
        #pragma unroll
        for (int g = 0; g < 2; ++g)
          #pragma unroll
          for (int e = 0; e < 8; ++e) {
            const float v = ac[g * 8 + e];
            const unsigned u = __float_as_uint(v);
            const float rem = v - __uint_as_float(u & 0xFFFF0000u);
            vh[g][e] = (unsigned short)(u >> 16);
            vl[g][e] = (unsigned short)(__float_as_uint(rem) >> 16);
          }
        *(u16x8*)((char*)Ah + nb + aw0) = vh[0];
        *(u16x8*)((char*)Ah + nb + aw1) = vh[1];
        *(u16x8*)((char*)Al + nb + aw0) = vl[0];
        *(u16x8*)((char*)Al + nb + aw1) = vl[1];
        if (t + 2 < nt) {
          #pragma unroll
          for (int q = 0; q < 4; ++q)
            *(float4*)&an[q * 4] = *(const float4*)(aptr + km + 64 + q * 4);
        }
      }
    }
    const int cb = cur * 8192;
    bf16x8 ah[4], al[4], bh[4], bl[4];
    #pragma unroll
    for (int i = 0; i < 4; ++i) {
      ah[i] = *(const bf16x8*)((const char*)Ah + cb + aRd[i]);
      al[i] = *(const bf16x8*)((const char*)Al + cb + aRd[i]);
      bh[i] = *(const bf16x8*)((const char*)Bh + cb + bRd[i]);
      bl[i] = *(const bf16x8*)((const char*)Bl + cb + bRd[i]);
    }
    #pragma unroll
    for (int i = 0; i < 4; ++i)
      #pragma unroll
      for (int j = 0; j < 4; ++j) {
        acc[i][j] = __builtin_amdgcn_mfma_f32_16x16x32_bf16(ah[i], bh[j], acc[i][j], 0, 0, 0);
        acc[i][j] = __builtin_amdgcn_mfma_f32_16x16x32_bf16(ah[i], bl[j], acc[i][j], 0, 0, 0);
        acc[i][j] = __builtin_amdgcn_mfma_f32_16x16x32_bf16(al[i], bh[j], acc[i][j], 0, 0, 0);
      }
    if (t + 1 < nt) {
      asm volatile("s_waitcnt vmcnt(0)" ::: "memory");
      __syncthreads();
      if constexpr (!APRE) {
        if (t + 2 < nt) {
          #pragma unroll
          for (int e = 0; e < 16; ++e) ac[e] = an[e];
        }
      }
      cur ^= 1;
    }
  }

  float* C = C0;
  int bnc = bn;
  if (bn >= NC) { C = C1; bnc = bn - NC; }

  #pragma unroll
  for (int i = 0; i < 4; ++i) {
    const int gr = bm + wm * 64 + i * 16 + quad * 4;
    #pragma unroll
    for (int j = 0; j < 4; ++j) {
      const int gc = bnc + wn * 64 + j * 16 + lr;
      float* cp = C + (size_t)gr * NC + gc;
      const float bv = (ACT == 1) ? bias[gc] : 0.f;
      #pragma unroll
      for (int r = 0; r < 4; ++r) {
        float v = acc[i][j][r];
        if (ACT == 1) v = softplus_f(v + bv);
        if (ATOMIC) atomicAdd(&cp[(size_t)r * NC], v);
        else        cp[(size_t)r * NC] = v;
      }
    }
  }
}

// GEMM1: [xc|z] = x @ W_in^T, A pre-split (APRE). Two half-grid launches
// (attribution): caller offsets A planes and C pointers by row.
__global__ __launch_bounds__(256)
void gemm_in_bf16x3(const unsigned short* __restrict__ Ahi_g,
                    const unsigned short* __restrict__ Alo_g, int lda,
                    const unsigned short* __restrict__ Bhi,
                    const unsigned short* __restrict__ Blo,
                    float* __restrict__ C0, float* __restrict__ C1,
                    int NC, int K, int klen) {
  gemm_body<false, 0, true>(nullptr, Ahi_g, Alo_g, lda, Bhi, Blo, nullptr,
                            C0, C1, NC, K, klen);
}

// GEMM4 (r10): out = y @ W_out^T, A = y bf16 planes (APRE), split-K=2,
// atomic (out pre-zeroed). r7-proven config: 512 blocks = 2/CU -> TLP.
// r9's no-split-K (256 blocks, 1/CU) measured 87us @ 23% MfmaUtil — reverted.
__global__ __launch_bounds__(256)
void gemm_out_bf16x3(const unsigned short* __restrict__ Ahi_g,
                     const unsigned short* __restrict__ Alo_g, int lda,
                     const unsigned short* __restrict__ Bhi,
                     const unsigned short* __restrict__ Blo,
                     float* __restrict__ C0,
                     int NC, int K, int klen) {
  gemm_body<true, 0, true>(nullptr, Ahi_g, Alo_g, lda, Bhi, Blo, nullptr,
                           C0, C0, NC, K, klen);
}

// ---- GEMM2: xp = xc2 @ W_xproj^T as MFMA bf16x3, APRE both sides ----
// r6-proven. M=4096, N=96 (tile 128x128, cols >=96 masked), K=2048 split 8.
__global__ __launch_bounds__(256)
void xproj_gemm_bf16x3(const unsigned short* __restrict__ Ahi_g,
                       const unsigned short* __restrict__ Alo_g,
                       const unsigned short* __restrict__ Bhi,
                       const unsigned short* __restrict__ Blo,
                       float* __restrict__ C, int klen) {
  __shared__ __align__(16) unsigned short Ah[2 * 128 * 32];
  __shared__ __align__(16) unsigned short Al[2 * 128 * 32];
  __shared__ __align__(16) unsigned short Bh[2 * 128 * 32];
  __shared__ __align__(16) unsigned short Bl[2 * 128 * 32];
  const int tid  = threadIdx.x;
  const int lane = tid & 63;
  const int wv   = tid >> 6;
  const int wm   = wv >> 1, wn = wv & 1;
  const int quad = lane >> 4, lr = lane & 15;
  const int bm = blockIdx.y * 128;
  const int kbeg = blockIdx.z * klen;

  int bOff[2], aOff[2], ldsO[2];
  #pragma unroll
  for (int j = 0; j < 2; ++j) {
    const int s   = (wv * 2 + j) * 64 + lane;
    const int row = s >> 2;
    const int c   = (s & 3) ^ ((row >> 1) & 3);
    bOff[j] = row * DI + c * 8;            // padded 128-row B, stride DI
    aOff[j] = (bm + row) * DI + c * 8;
    ldsO[j] = (wv * 2 + j) << 10;
  }
  int aRd[4], bRd[4];
  #pragma unroll
  for (int i = 0; i < 4; ++i) {
    const int ra = wm * 64 + i * 16 + lr;
    aRd[i] = (ra * 4 + (quad ^ ((ra >> 1) & 3))) << 4;
    const int rb = wn * 64 + i * 16 + lr;
    bRd[i] = (rb * 4 + (quad ^ ((rb >> 1) & 3))) << 4;
  }

  f32x4 acc[4][4];
  #pragma unroll
  for (int i = 0; i < 4; ++i)
    #pragma unroll
    for (int j = 0; j < 4; ++j)
      acc[i][j] = (f32x4){0.f, 0.f, 0.f, 0.f};

  const int nt = klen / 32;
  #pragma unroll
  for (int j = 0; j < 2; ++j) {
    gl2lds16(Ahi_g + (size_t)aOff[j] + kbeg, (char*)Ah + ldsO[j]);
    gl2lds16(Alo_g + (size_t)aOff[j] + kbeg, (char*)Al + ldsO[j]);
    gl2lds16(Bhi   + (size_t)bOff[j] + kbeg, (char*)Bh + ldsO[j]);
    gl2lds16(Blo   + (size_t)bOff[j] + kbeg, (char*)Bl + ldsO[j]);
  }
  asm volatile("s_waitcnt vmcnt(0)" ::: "memory");
  __syncthreads();

  int cur = 0;
  #pragma unroll 1
  for (int t = 0; t < nt; ++t) {
    const int km = kbeg + t * 32;
    if (t + 1 < nt) {
      const int nb = (cur ^ 1) * 8192;
      #pragma unroll
      for (int j = 0; j < 2; ++j) {
        gl2lds16(Ahi_g + (size_t)aOff[j] + km + 32, (char*)Ah + nb + ldsO[j]);
        gl2lds16(Alo_g + (size_t)aOff[j] + km + 32, (char*)Al + nb + ldsO[j]);
        gl2lds16(Bhi   + (size_t)bOff[j] + km + 32, (char*)Bh + nb + ldsO[j]);
        gl2lds16(Blo   + (size_t)bOff[j] + km + 32, (char*)Bl + nb + ldsO[j]);
      }
    }
    const int cb = cur * 8192;
    bf16x8 ah[4], al[4], bh[4], bl[4];
    #pragma unroll
    for (int i = 0; i < 4; ++i) {
      ah[i] = *(const bf16x8*)((const char*)Ah + cb + aRd[i]);
      al[i] = *(const bf16x8*)((const char*)Al + cb + aRd[i]);
      bh[i] = *(const bf16x8*)((const char*)Bh + cb + bRd[i]);
      bl[i] = *(const bf16x8*)((const char*)Bl + cb + bRd[i]);
    }
    #pragma unroll
    for (int i = 0; i < 4; ++i)
      #pragma unroll
      for (int j = 0; j < 4; ++j) {
        acc[i][j] = __builtin_amdgcn_mfma_f32_16x16x32_bf16(ah[i], bh[j], acc[i][j], 0, 0, 0);
        acc[i][j] = __builtin_amdgcn_mfma_f32_16x16x32_bf16(ah[i], bl[j], acc[i][j], 0, 0, 0);
        acc[i][j] = __builtin_amdgcn_mfma_f32_16x16x32_bf16(al[i], bh[j], acc[i][j], 0, 0, 0);
      }
    if (t + 1 < nt) {
      asm volatile("s_waitcnt vmcnt(0)" ::: "memory");
      __syncthreads();
      cur ^= 1;
    }
  }

  #pragma unroll
  for (int i = 0; i < 4; ++i) {
    const int gr = bm + wm * 64 + i * 16 + quad * 4;
    #pragma unroll
    for (int j = 0; j < 4; ++j) {
      const int gc = wn * 64 + j * 16 + lr;
      if (gc < NXP) {
        float* cp = C + (size_t)gr * NXP + gc;
        #pragma unroll
        for (int r = 0; r < 4; ++r)
          atomicAdd(&cp[(size_t)r * NXP], acc[i][j][r]);
      }
    }
  }
}

// Causal depthwise conv (width 4) + bias + SiLU.
// r10: thread = 4 consecutive l x 4 d (float4): 7 row-reads per 4 output
// rows (was 4 reads per 1) -> ~2.3x less nominal read traffic.
__global__ __launch_bounds__(256)
void conv_silu_kernel(const float* __restrict__ xc_raw, const float* __restrict__ cw,
                      const float* __restrict__ cb, float* __restrict__ xc2,
                      unsigned short* __restrict__ xc2hi,
                      unsigned short* __restrict__ xc2lo) {
  const int tid = blockIdx.x * 256 + threadIdx.x;   // NB*(LSEQ/4)*(DI/4)
  const int d4 = tid & (DI / 4 - 1);                // 9 bits
  const int lt = (tid >> 9) & (LSEQ / 4 - 1);       // 9 bits
  const int b  = tid >> 18;
  const int l0 = lt << 2;
  const size_t rowb = ((size_t)b * LSEQ + l0) * DI + d4 * 4;
  float4 v[7];
  #pragma unroll
  for (int j = 0; j < 7; ++j) {
    const int ls = l0 - 3 + j;
    v[j] = (ls >= 0) ? *(const float4*)(xc_raw + rowb + ((long long)j - 3) * DI)
                     : make_float4(0.f, 0.f, 0.f, 0.f);
  }
  const float4 bias = *(const float4*)(cb + d4 * 4);
  float4 w[4];
  #pragma unroll
  for (int k = 0; k < 4; ++k) w[k] = *(const float4*)(cw + (d4 * 4 + k) * 4);
  #pragma unroll
  for (int t = 0; t < 4; ++t) {
    float o[4];
    #pragma unroll
    for (int k = 0; k < 4; ++k) {
      float acc = fmaf(w[k].x, ((const float*)&v[t])[k], ((const float*)&bias)[k]);
      acc = fmaf(w[k].y, ((const float*)&v[t + 1])[k], acc);
      acc = fmaf(w[k].z, ((const float*)&v[t + 2])[k], acc);
      acc = fmaf(w[k].w, ((const float*)&v[t + 3])[k], acc);
      o[k] = silu_f(acc);
    }
    const size_t ob = rowb + (size_t)t * DI;
    *(float4*)(xc2 + ob) = make_float4(o[0], o[1], o[2], o[3]);
    ushort4 h, lo4;
    h.x = f2bf(o[0]); h.y = f2bf(o[1]); h.z = f2bf(o[2]); h.w = f2bf(o[3]);
    lo4.x = f2bf(o[0] - bf2f(h.x)); lo4.y = f2bf(o[1] - bf2f(h.y));
    lo4.z = f2bf(o[2] - bf2f(h.z)); lo4.w = f2bf(o[3] - bf2f(h.w));
    *(ushort4*)(xc2hi + ob) = h;
    *(ushort4*)(xc2lo + ob) = lo4;
  }
}

// ---- Pass 1 (lite): per-chunk summaries ONLY ----
__global__ __launch_bounds__(256)
void scan_chunk_kernel(const float* __restrict__ xc2, const float* __restrict__ dtb,
                       const float* __restrict__ xp, const float* __restrict__ A_log,
                       float* __restrict__ hloc, float* __restrict__ totdt) {
  __shared__ float sB[LC][DSTATE];   // 4 KB
  const int d = blockIdx.x * 256 + threadIdx.x;
  const int b = blockIdx.y;
  const int c = blockIdx.z;

  float A[DSTATE], h[DSTATE];
  #pragma unroll
  for (int n = 0; n < DSTATE; ++n) {
    A[n] = -__expf(A_log[(size_t)d * DSTATE + n]);
    h[n] = 0.f;
  }

  {
    const float* xpb = xp + ((size_t)b * LSEQ + (size_t)c * LC) * NXP + DTRANK;
    const int row = threadIdx.x >> 2, q = threadIdx.x & 3;
    *(float4*)&sB[row][q * 4] = *(const float4*)&xpb[(size_t)row * NXP + q * 4];
  }
  __syncthreads();

  const size_t cbase = ((size_t)b * LSEQ + (size_t)c * LC) * DI + d;
  float cum = 0.f;
  constexpr int U = 4;
  float cdt[U], cx[U];
  #pragma unroll
  for (int u = 0; u < U; ++u) {
    cdt[u] = dtb[cbase + (size_t)u * DI];
    cx[u]  = xc2[cbase + (size_t)u * DI];
  }

  #pragma unroll 1
  for (int g = 0; g < LC; g += U) {
    float ndt[U], nx[U];
    if (g + U < LC) {
      #pragma unroll
      for (int u = 0; u < U; ++u) {
        ndt[u] = dtb[cbase + (size_t)(g + U + u) * DI];
        nx[u]  = xc2[cbase + (size_t)(g + U + u) * DI];
      }
    }
    #pragma unroll
    for (int u = 0; u < U; ++u) {
      const int t = g + u;
      const float dt = cdt[u];
      const float dx = dt * cx[u];
      cum += dt;
      #pragma unroll
      for (int n = 0; n < DSTATE; ++n) {
        const float ab = __expf(dt * A[n]);
        h[n] = fmaf(ab, h[n], dx * sB[t][n]);
      }
    }
    if (g + U < LC) {
      #pragma unroll
      for (int u = 0; u < U; ++u) { cdt[u] = ndt[u]; cx[u] = nx[u]; }
    }
  }

  const size_t hbase = ((size_t)(b * CHUNKS + c)) * DSTATE * DI + d;
  #pragma unroll
  for (int n = 0; n < DSTATE; ++n) hloc[hbase + (size_t)n * DI] = h[n];
  totdt[((size_t)(b * CHUNKS + c)) * DI + d] = cum;
}

// Pass 2: carry propagation (in-place local-end -> carry-in). Unchanged.
__global__ __launch_bounds__(256)
void scan_carry_kernel(float* __restrict__ hloc, const float* __restrict__ totdt,
                       const float* __restrict__ A_log) {
  const int tid = blockIdx.x * 256 + threadIdx.x;   // NB*DSTATE*DI
  const int d = tid & (DI - 1);
  const int n = (tid >> 11) & 15;
  const int b = tid >> 15;
  const float An = -__expf(A_log[(size_t)d * DSTATE + n]);
  float h = 0.f;
  float le = hloc[((size_t)(b * CHUNKS) * DSTATE + n) * DI + d];
  float td = totdt[(size_t)(b * CHUNKS) * DI + d];
  for (int c = 0; c < CHUNKS; ++c) {
    const size_t ix = ((size_t)(b * CHUNKS + c) * DSTATE + n) * DI + d;
    float nle = 0.f, ntd = 0.f;
    if (c + 1 < CHUNKS) {
      nle = hloc[ix + (size_t)DSTATE * DI];
      ntd = totdt[(size_t)(b * CHUNKS + c + 1) * DI + d];
    }
    hloc[ix] = h;
    h = fmaf(__expf(An * td), h, le);
    le = nle; td = ntd;
  }
}

// ---- Pass 3: direct recurrence from carry-in; emit y as bf16 hi/lo ----
__global__ __launch_bounds__(256)
void scan_final_kernel(const float* __restrict__ xc2, const float* __restrict__ dtb,
                       const float* __restrict__ xp, const float* __restrict__ zbuf,
                       const float* __restrict__ A_log, const float* __restrict__ Dp,
                       const float* __restrict__ hloc,
                       unsigned short* __restrict__ yhi,
                       unsigned short* __restrict__ ylo) {
  __shared__ float sbc[LC][32];   // 8 KB: [t][0:16)=B, [16:32)=C
  const int tid = threadIdx.x;
  const int d = blockIdx.x * 256 + tid;
  const int b = blockIdx.y;
  const int c = blockIdx.z;

  float A[DSTATE], h[DSTATE];
  {
    const float* hp = hloc + ((size_t)(b * CHUNKS + c)) * DSTATE * DI + d;
    const float* ap = A_log + (size_t)d * DSTATE;
    #pragma unroll
    for (int n = 0; n < DSTATE; ++n) {
      A[n] = -__expf(ap[n]);
      h[n] = hp[(size_t)n * DI];     // carry-in state
    }
  }
  {
    const float* xpb = xp + ((size_t)b * LSEQ + (size_t)c * LC) * NXP + DTRANK;
    #pragma unroll
    for (int kk = 0; kk < 2; ++kk) {
      const int slot = tid + kk * 256;
      const int row = slot >> 3, q4 = (slot & 7) << 2;
      *(float4*)&sbc[row][q4] = *(const float4*)&xpb[(size_t)row * NXP + q4];
    }
  }
  __syncthreads();

  const float Dd = Dp[d];
  const size_t cbase = ((size_t)b * LSEQ + (size_t)c * LC) * DI + d;
  constexpr int U = 4;
  float cdt[U], cx[U], cz[U];
  #pragma unroll
  for (int u = 0; u < U; ++u) {
    cdt[u] = dtb[cbase + (size_t)u * DI];
    cx[u]  = xc2[cbase + (size_t)u * DI];
    cz[u]  = zbuf[cbase + (size_t)u * DI];
  }

  #pragma unroll 1
  for (int g = 0; g < LC; g += U) {
    float ndt[U], nx[U], nz[U];
    if (g + U < LC) {
      #pragma unroll
      for (int u = 0; u < U; ++u) {
        ndt[u] = dtb[cbase + (size_t)(g + U + u) * DI];
        nx[u]  = xc2[cbase + (size_t)(g + U + u) * DI];
        nz[u]  = zbuf[cbase + (size_t)(g + U + u) * DI];
      }
    }
    #pragma unroll
    for (int u = 0; u < U; ++u) {
      const int t = g + u;
      const float dt = cdt[u];
      const float dx = dt * cx[u];
      #pragma unroll
      for (int n = 0; n < DSTATE; ++n) {
        const float ab = __expf(dt * A[n]);
        h[n] = fmaf(ab, h[n], dx * sbc[t][n]);
      }
      float p[DSTATE];
      #pragma unroll
      for (int n = 0; n < DSTATE; ++n) p[n] = h[n] * sbc[t][DSTATE + n];
      #pragma unroll
      for (int s = 1; s < DSTATE; s <<= 1)
        #pragma unroll
        for (int n = 0; n < DSTATE; n += 2 * s) p[n] += p[n + s];
      const float yv = (p[0] + cx[u] * Dd) * silu_f(cz[u]);
      const size_t base = cbase + (size_t)t * DI;
      const unsigned short hh = f2bf(yv);
      yhi[base] = hh;
      ylo[base] = f2bf(yv - bf2f(hh));
    }
    if (g + U < LC) {
      #pragma unroll
      for (int u = 0; u < U; ++u) { cdt[u] = ndt[u]; cx[u] = nx[u]; cz[u] = nz[u]; }
    }
  }
}

extern "C" void kernel_launch(void* const* d_in, const int* in_sizes, int n_in,
                              void* d_out, int out_size, void* d_ws, size_t ws_size,
                              hipStream_t stream) {
  const float* x      = (const float*)d_in[0];
  const float* W_in   = (const float*)d_in[1];
  const float* conv_w = (const float*)d_in[2];
  const float* conv_b = (const float*)d_in[3];
  const float* W_xproj= (const float*)d_in[4];
  const float* W_dt   = (const float*)d_in[5];
  const float* b_dt   = (const float*)d_in[6];
  const float* A_log  = (const float*)d_in[7];
  const float* Dp     = (const float*)d_in[8];
  const float* W_out  = (const float*)d_in[9];
  float* out = (float*)d_out;
  float* ws  = (float*)d_ws;

  // ws layout (floats), ~154 MB:
  //   xc_raw[SEG] | zbuf[SEG] | xc2[SEG] | dtb[SEG] | xp | hloc | totdt | pools
  // Overlays (time-disjoint):
  //   Whi/Wlo over dtb        — consumed by GEMM1 (dtb written later by dt_gemm).
  //   xc2hi/xc2lo over dtb    — conv..xproj window, dead before dt_gemm.
  //   xhi/xlo over xc2        — prep..GEMM1 window; conv overwrites xc2.
  //   yhi/ylo over xc_raw     — scan_final output, consumed by GEMM4 APRE.
  const size_t SEG = (size_t)NB * LSEQ * DI;            // 8,388,608
  float* xc_raw = ws;
  float* zbuf   = ws + SEG;
  float* xc2    = ws + 2 * SEG;
  float* dtb    = ws + 3 * SEG;
  float* xp     = ws + 4 * SEG;                         // 393,216
  float* hloc   = xp + (size_t)MROWS * NXP;             // 2,097,152
  float* totdt  = hloc + (size_t)NB * CHUNKS * DSTATE * DI;  // 131,072
  float* wpool  = totdt + (size_t)NB * CHUNKS * DI;

  unsigned short* Whi = (unsigned short*)dtb;           // overlay (dead before conv)
  unsigned short* Wlo = Whi + (size_t)2 * DI * DMODEL;

  unsigned short* xc2hi = (unsigned short*)dtb;         // overlay (conv..xproj window)
  unsigned short* xc2lo = xc2hi + (size_t)MROWS * DI;

  unsigned short* xhi = (unsigned short*)xc2;           // overlay (dead until conv)
  unsigned short* xlo = xhi + (size_t)MROWS * DMODEL;

  unsigned short* yhi = (unsigned short*)xc_raw;        // overlay (scan_final..GEMM4)
  unsigned short* ylo = yhi + (size_t)MROWS * DI;

  unsigned short* Wohi = (unsigned short*)wpool;        // 2,097,152 ushort
  unsigned short* Wolo = Wohi + (size_t)DMODEL * DI;
  unsigned short* wdhi = Wolo + (size_t)DMODEL * DI;    // 131,072 ushort
  unsigned short* wdlo = wdhi + (size_t)DI * DTRANK;
  unsigned short* wxhi = wdlo + (size_t)DI * DTRANK;    // 262,144 ushort (padded 128xDI)
  unsigned short* wxlo = wxhi + (size_t)128 * DI;

  dim3 blk(256);

  // Prep: weight + x splits (incl. padded W_xproj), zero xp and out
  const int prep_blocks = (2*DI*DMODEL/4 + DI*DTRANK/4 + DMODEL*DI/4
                           + MROWS*DMODEL/4 + 128*DI/4
                           + MROWS*NXP/4 + MROWS*DMODEL/4) / 256;
  prep_kernel<<<prep_blocks, blk, 0, stream>>>(
      W_in, W_dt, W_out, x, W_xproj, Whi, Wlo, wdhi, wdlo, Wohi, Wolo,
      xhi, xlo, wxhi, wxlo, xp, out);

  // GEMM1 fused: [xc | z] = x @ W_in^T  (128^2, A pre-split; K=1024)
  // Two half-grid launches (rows 0..2047 / 2048..4095) for rocprof
  // attribution — offset A planes and C pointers; body unchanged.
  const size_t rowHalf = (size_t)(MROWS / 2);
  gemm_in_bf16x3<<<dim3(2*DI/128, MROWS/256, 1), blk, 0, stream>>>(
      xhi, xlo, DMODEL, Whi, Wlo, xc_raw, zbuf, DI, DMODEL, DMODEL);
  gemm_in_bf16x3<<<dim3(2*DI/128, MROWS/256, 1), blk, 0, stream>>>(
      xhi + rowHalf * DMODEL, xlo + rowHalf * DMODEL, DMODEL, Whi, Wlo,
      xc_raw + rowHalf * DI, zbuf + rowHalf * DI, DI, DMODEL, DMODEL);

  // conv + bias + SiLU (4l x 4d per thread) + bf16 hi/lo planes of xc2
  conv_silu_kernel<<<(NB*(LSEQ/4)*(DI/4))/256, blk, 0, stream>>>(
      xc_raw, conv_w, conv_b, xc2, xc2hi, xc2lo);

  // GEMM2: xp = xc2 @ W_xproj^T — MFMA bf16x3, split-K=8 atomic (xp zeroed)
  xproj_gemm_bf16x3<<<dim3(1, MROWS/128, 8), blk, 0, stream>>>(
      xc2hi, xc2lo, wxhi, wxlo, xp, DI/8);

  // GEMM3: dt = softplus(dt_lr @ W_dt^T + b_dt) — dedicated LDS-free kernel
  dt_gemm_kernel<<<dim3(DI/128, MROWS/128, 1), blk, 0, stream>>>(
      xp, wdhi, wdlo, b_dt, dtb);

  // Scan: summaries -> carries -> direct recurrence emitting y bf16 planes
  scan_chunk_kernel<<<dim3(DI/256, NB, CHUNKS), blk, 0, stream>>>(
      xc2, dtb, xp, A_log, hloc, totdt);
  scan_carry_kernel<<<(NB*DI*DSTATE)/256, blk, 0, stream>>>(hloc, totdt, A_log);
  scan_final_kernel<<<dim3(DI/256, NB, CHUNKS), blk, 0, stream>>>(
      xc2, dtb, xp, zbuf, A_log, Dp, hloc, yhi, ylo);

  // GEMM4: out = y @ W_out^T — A = y bf16 planes (APRE), split-K=2, atomic
  // (out zeroed in prep). 512 blocks = 2/CU.
  gemm_out_bf16x3<<<dim3(DMODEL/128, MROWS/128, 2), blk, 0, stream>>>(
      yhi, ylo, DI, Wohi, Wolo, out, DMODEL, DI, DI/2);
}

// Round 11
// 420.553 us; speedup vs baseline: 1.0614x; 1.0108x over previous
//
#include <hip/hip_runtime.h>
#include <cstddef>
#include <cstdint>

// Problem constants (match reference)
#define DMODEL 1024
#define DI     2048      // D_INNER
#define LSEQ   2048
#define NB     2
#define DSTATE 16
#define DTRANK 64
#define NXP    96        // DT_RANK + 2*D_STATE
#define MROWS  (NB*LSEQ) // 4096 GEMM rows
#define CHUNKS 32
#define LC     (LSEQ/CHUNKS)   // 64

typedef __attribute__((ext_vector_type(8))) short bf16x8;
typedef __attribute__((ext_vector_type(8))) unsigned short u16x8;
typedef __attribute__((ext_vector_type(4))) float f32x4;

__device__ __forceinline__ float silu_f(float v) {
  return v / (1.f + __expf(-v));
}
__device__ __forceinline__ float softplus_f(float v) {
  return (v > 20.f) ? v : log1pf(__expf(v));
}
__device__ __forceinline__ unsigned short f2bf(float f) {   // RNE
  unsigned u = __float_as_uint(f);
  unsigned r = (u + 0x7FFFu + ((u >> 16) & 1u)) >> 16;
  return (unsigned short)r;
}
__device__ __forceinline__ float bf2f(unsigned short h) {
  return __uint_as_float(((unsigned)h) << 16);
}
__device__ __forceinline__ void gl2lds16(const void* g, void* l) {
  __builtin_amdgcn_global_load_lds(
      (const __attribute__((address_space(1))) void*)g,
      (__attribute__((address_space(3))) void*)l, 16, 0, 0);
}

// Prep: split W_in/W_dt/W_out/x/W_xproj(128-row zero-padded) to bf16 hi/lo
// (RNE) + zero xp and out.
__global__ __launch_bounds__(256)
void prep_kernel(const float* __restrict__ W_in, const float* __restrict__ W_dt,
                 const float* __restrict__ W_out, const float* __restrict__ x,
                 const float* __restrict__ W_xproj,
                 unsigned short* __restrict__ Whi, unsigned short* __restrict__ Wlo,
                 unsigned short* __restrict__ wdhi, unsigned short* __restrict__ wdlo,
                 unsigned short* __restrict__ Wohi, unsigned short* __restrict__ Wolo,
                 unsigned short* __restrict__ xhi, unsigned short* __restrict__ xlo,
                 unsigned short* __restrict__ wxhi, unsigned short* __restrict__ wxlo,
                 float* __restrict__ xp, float* __restrict__ out) {
  const int N_WIN  = 2*DI*DMODEL/4;   // 1,048,576 float4
  const int N_WDT  = DI*DTRANK/4;     //    32,768
  const int N_WOUT = DMODEL*DI/4;     //   524,288
  const int N_X    = MROWS*DMODEL/4;  // 1,048,576
  const int N_WX   = 128*DI/4;        //    65,536 (padded to 128 rows)
  const int N_XP   = MROWS*NXP/4;     //    98,304
  const int N_OUT  = MROWS*DMODEL/4;  // 1,048,576
  int i = blockIdx.x * 256 + threadIdx.x;
  const float* src = nullptr;
  unsigned short *hi = nullptr, *lo = nullptr;
  if (i < N_WIN)  { src = W_in;  hi = Whi;  lo = Wlo;  }
  else {
    i -= N_WIN;
    if (i < N_WDT)  { src = W_dt;  hi = wdhi; lo = wdlo; }
    else {
      i -= N_WDT;
      if (i < N_WOUT) { src = W_out; hi = Wohi; lo = Wolo; }
      else {
        i -= N_WOUT;
        if (i < N_X) { src = x; hi = xhi; lo = xlo; }
        else {
          i -= N_X;
          if (i < N_WX) {
            // W_xproj split, rows 96..127 zero-padded
            const int row = (i << 2) >> 11;     // /DI per-element row
            float4 v = make_float4(0.f, 0.f, 0.f, 0.f);
            if (row < NXP) v = ((const float4*)W_xproj)[i];
            ushort4 h, l;
            h.x = f2bf(v.x); h.y = f2bf(v.y); h.z = f2bf(v.z); h.w = f2bf(v.w);
            l.x = f2bf(v.x - bf2f(h.x)); l.y = f2bf(v.y - bf2f(h.y));
            l.z = f2bf(v.z - bf2f(h.z)); l.w = f2bf(v.w - bf2f(h.w));
            ((ushort4*)wxhi)[i] = h; ((ushort4*)wxlo)[i] = l;
            return;
          }
          i -= N_WX;
          if (i < N_XP) { ((float4*)xp)[i] = make_float4(0.f,0.f,0.f,0.f); }
          else {
            i -= N_XP;
            if (i < N_OUT) ((float4*)out)[i] = make_float4(0.f,0.f,0.f,0.f);
          }
          return;
        }
      }
    }
  }
  float4 v = ((const float4*)src)[i];
  ushort4 h, l;
  h.x = f2bf(v.x); h.y = f2bf(v.y); h.z = f2bf(v.z); h.w = f2bf(v.w);
  l.x = f2bf(v.x - bf2f(h.x)); l.y = f2bf(v.y - bf2f(h.y));
  l.z = f2bf(v.z - bf2f(h.z)); l.w = f2bf(v.w - bf2f(h.w));
  ((ushort4*)hi)[i] = h; ((ushort4*)lo)[i] = l;
}

// ---- Dedicated dt GEMM: dt = softplus(xp[:,0:64] @ W_dt^T + b_dt) ----
// K=64 in registers: NO LDS, NO barriers. r4-proven.
__global__ __launch_bounds__(256)
void dt_gemm_kernel(const float* __restrict__ xp_,
                    const unsigned short* __restrict__ wdhi,
                    const unsigned short* __restrict__ wdlo,
                    const float* __restrict__ bias,
                    float* __restrict__ dtb_) {
  const int tid  = threadIdx.x;
  const int lane = tid & 63;
  const int wv   = tid >> 6;
  const int wm   = wv >> 1, wn = wv & 1;
  const int quad = lane >> 4, lr = lane & 15;
  const int bm = blockIdx.y * 128, bn = blockIdx.x * 128;

  f32x4 acc[4][4];
  #pragma unroll
  for (int i = 0; i < 4; ++i)
    #pragma unroll
    for (int j = 0; j < 4; ++j)
      acc[i][j] = (f32x4){0.f, 0.f, 0.f, 0.f};

  #pragma unroll
  for (int kk = 0; kk < 2; ++kk) {
    const int k0 = kk * 32 + quad * 8;   // lane's k-octet within K=64
    bf16x8 ah[4], al[4], bh[4], bl[4];
    #pragma unroll
    for (int i = 0; i < 4; ++i) {
      const int row = bm + wm * 64 + i * 16 + lr;
      const float* ap = xp_ + (size_t)row * NXP + k0;
      const float4 v0 = *(const float4*)ap;
      const float4 v1 = *(const float4*)(ap + 4);
      const float av[8] = {v0.x, v0.y, v0.z, v0.w, v1.x, v1.y, v1.z, v1.w};
      bf16x8 h, l;
      #pragma unroll
      for (int e = 0; e < 8; ++e) {
        const float v = av[e];
        const unsigned u = __float_as_uint(v);
        const float rem = v - __uint_as_float(u & 0xFFFF0000u);
        h[e] = (short)(u >> 16);
        l[e] = (short)(__float_as_uint(rem) >> 16);
      }
      ah[i] = h; al[i] = l;
    }
    #pragma unroll
    for (int j = 0; j < 4; ++j) {
      const int col = bn + wn * 64 + j * 16 + lr;
      bh[j] = *(const bf16x8*)(wdhi + (size_t)col * DTRANK + k0);
      bl[j] = *(const bf16x8*)(wdlo + (size_t)col * DTRANK + k0);
    }
    #pragma unroll
    for (int i = 0; i < 4; ++i)
      #pragma unroll
      for (int j = 0; j < 4; ++j) {
        acc[i][j] = __builtin_amdgcn_mfma_f32_16x16x32_bf16(ah[i], bh[j], acc[i][j], 0, 0, 0);
        acc[i][j] = __builtin_amdgcn_mfma_f32_16x16x32_bf16(ah[i], bl[j], acc[i][j], 0, 0, 0);
        acc[i][j] = __builtin_amdgcn_mfma_f32_16x16x32_bf16(al[i], bh[j], acc[i][j], 0, 0, 0);
      }
  }

  #pragma unroll
  for (int i = 0; i < 4; ++i) {
    const int gr = bm + wm * 64 + i * 16 + quad * 4;
    #pragma unroll
    for (int j = 0; j < 4; ++j) {
      const int gc = bn + wn * 64 + j * 16 + lr;
      float* cp = dtb_ + (size_t)gr * DI + gc;
      const float bv = bias[gc];
      #pragma unroll
      for (int r = 0; r < 4; ++r)
        cp[(size_t)r * DI] = softplus_f(acc[i][j][r] + bv);
    }
  }
}

// ---- 128x128 bf16x3 GEMM body (cvt / APRE), 4 waves, BK=32, dbuf ----
// r2-proven schedule. r11: bm/bn/kbeg hoisted to wrappers so gemm_out can
// swap grid axes for XCD L2 locality (T1). Body logic unchanged.
template<bool ATOMIC, int ACT, bool APRE>
__device__ __forceinline__
void gemm_body(const float* __restrict__ A,
               const unsigned short* __restrict__ Ahi_g,
               const unsigned short* __restrict__ Alo_g,
               int lda,
               const unsigned short* __restrict__ Bhi, const unsigned short* __restrict__ Blo,
               const float* __restrict__ bias,
               float* __restrict__ C0, float* __restrict__ C1,
               int NC, int K, int klen, int bm, int bn, int kbeg) {
  __shared__ __align__(16) unsigned short Ah[2 * 128 * 32];
  __shared__ __align__(16) unsigned short Al[2 * 128 * 32];
  __shared__ __align__(16) unsigned short Bh[2 * 128 * 32];
  __shared__ __align__(16) unsigned short Bl[2 * 128 * 32];
  const int tid  = threadIdx.x;
  const int lane = tid & 63;
  const int wv   = tid >> 6;
  const int wm   = wv >> 1, wn = wv & 1;
  const int quad = lane >> 4, lr = lane & 15;

  int bOff[2], aOffp[2], ldsO[2];
  #pragma unroll
  for (int j = 0; j < 2; ++j) {
    const int s   = (wv * 2 + j) * 64 + lane;
    const int row = s >> 2;
    const int c   = (s & 3) ^ ((row >> 1) & 3);
    bOff[j]  = (bn + row) * K + c * 8;
    aOffp[j] = (bm + row) * lda + c * 8;
    ldsO[j]  = (wv * 2 + j) << 10;
  }
  const int ar = tid >> 1;
  const int ahalf = tid & 1;
  const int asw = (ar >> 1) & 3;
  const int aw0 = (ar * 4 + ((ahalf * 2)     ^ asw)) << 4;
  const int aw1 = (ar * 4 + ((ahalf * 2 + 1) ^ asw)) << 4;
  const float* aptr = (!APRE) ? (A + (size_t)(bm + ar) * lda + ahalf * 16) : nullptr;

  int aRd[4], bRd[4];
  #pragma unroll
  for (int i = 0; i < 4; ++i) {
    const int ra = wm * 64 + i * 16 + lr;
    aRd[i] = (ra * 4 + (quad ^ ((ra >> 1) & 3))) << 4;
    const int rb = wn * 64 + i * 16 + lr;
    bRd[i] = (rb * 4 + (quad ^ ((rb >> 1) & 3))) << 4;
  }

  f32x4 acc[4][4];
  #pragma unroll
  for (int i = 0; i < 4; ++i)
    #pragma unroll
    for (int j = 0; j < 4; ++j)
      acc[i][j] = (f32x4){0.f, 0.f, 0.f, 0.f};

  const int nt = klen / 32;
  float ac[16], an[16];

  if constexpr (APRE) {
    #pragma unroll
    for (int j = 0; j < 2; ++j) {
      gl2lds16(Bhi   + (size_t)bOff[j]  + kbeg, (char*)Bh + ldsO[j]);
      gl2lds16(Blo   + (size_t)bOff[j]  + kbeg, (char*)Bl + ldsO[j]);
      gl2lds16(Ahi_g + (size_t)aOffp[j] + kbeg, (char*)Ah + ldsO[j]);
      gl2lds16(Alo_g + (size_t)aOffp[j] + kbeg, (char*)Al + ldsO[j]);
    }
  } else {
    #pragma unroll
    for (int j = 0; j < 2; ++j) {
      gl2lds16(Bhi + (size_t)bOff[j] + kbeg, (char*)Bh + ldsO[j]);
      gl2lds16(Blo + (size_t)bOff[j] + kbeg, (char*)Bl + ldsO[j]);
    }
    #pragma unroll
    for (int q = 0; q < 4; ++q)
      *(float4*)&ac[q * 4] = *(const float4*)(aptr + kbeg + q * 4);
    u16x8 vh[2], vl[2];
    #pragma unroll
    for (int g = 0; g < 2; ++g)
      #pragma unroll
      for (int e = 0; e < 8; ++e) {
        const float v = ac[g * 8 + e];
        const unsigned u = __float_as_uint(v);
        const float rem = v - __uint_as_float(u & 0xFFFF0000u);
        vh[g][e] = (unsigned short)(u >> 16);
        vl[g][e] = (unsigned short)(__float_as_uint(rem) >> 16);
      }
    *(u16x8*)((char*)Ah + aw0) = vh[0];
    *(u16x8*)((char*)Ah + aw1) = vh[1];
    *(u16x8*)((char*)Al + aw0) = vl[0];
    *(u16x8*)((char*)Al + aw1) = vl[1];
    if (nt > 1) {
      #pragma unroll
      for (int q = 0; q < 4; ++q)
        *(float4*)&ac[q * 4] = *(const float4*)(aptr + kbeg + 32 + q * 4);
    }
  }
  asm volatile("s_waitcnt vmcnt(0)" ::: "memory");
  __syncthreads();

  int cur = 0;
  #pragma unroll 1
  for (int t = 0; t < nt; ++t) {
    const int km = kbeg + t * 32;
    if (t + 1 < nt) {
      const int nb = (cur ^ 1) * 8192;
      if constexpr (APRE) {
        #pragma unroll
        for (int j = 0; j < 2; ++j) {
          gl2lds16(Bhi   + (size_t)bOff[j]  + km + 32, (char*)Bh + nb + ldsO[j]);
          gl2lds16(Blo   + (size_t)bOff[j]  + km + 32, (char*)Bl + nb + ldsO[j]);
          gl2lds16(Ahi_g + (size_t)aOffp[j] + km + 32, (char*)Ah + nb + ldsO[j]);
          gl2lds16(Alo_g + (size_t)aOffp[j] + km + 32, (char*)Al + nb + ldsO[j]);
        }
      } else {
        #pragma unroll
        for (int j = 0; j < 2; ++j) {
          gl2lds16(Bhi + (size_t)bOff[j] + km + 32, (char*)Bh + nb + ldsO[j]);
          gl2lds16(Blo + (size_t)bOff[j] + km + 32, (char*)Bl + nb + ldsO[j]);
        }
        u16x8 vh[2], vl[2];
        #pragma unroll
        for (int g = 0; g < 2; ++g)
          #pragma unroll
          for (int e = 0; e < 8; ++e) {
            const float v = ac[g * 8 + e];
            const unsigned u = __float_as_uint(v);
            const float rem = v - __uint_as_float(u & 0xFFFF0000u);
            vh[g][e] = (unsigned short)(u >> 16);
            vl[g][e] = (unsigned short)(__float_as_uint(rem) >> 16);
          }
        *(u16x8*)((char*)Ah + nb + aw0) = vh[0];
        *(u16x8*)((char*)Ah + nb + aw1) = vh[1];
        *(u16x8*)((char*)Al + nb + aw0) = vl[0];
        *(u16x8*)((char*)Al + nb + aw1) = vl[1];
        if (t + 2 < nt) {
          #pragma unroll
          for (int q = 0; q < 4; ++q)
            *(float4*)&an[q * 4] = *(const float4*)(aptr + km + 64 + q * 4);
        }
      }
    }
    const int cb = cur * 8192;
    bf16x8 ah[4], al[4], bh[4], bl[4];
    #pragma unroll
    for (int i = 0; i < 4; ++i) {
      ah[i] = *(const bf16x8*)((const char*)Ah + cb + aRd[i]);
      al[i] = *(const bf16x8*)((const char*)Al + cb + aRd[i]);
      bh[i] = *(const bf16x8*)((const char*)Bh + cb + bRd[i]);
      bl[i] = *(const bf16x8*)((const char*)Bl + cb + bRd[i]);
    }
    #pragma unroll
    for (int i = 0; i < 4; ++i)
      #pragma unroll
      for (int j = 0; j < 4; ++j) {
        acc[i][j] = __builtin_amdgcn_mfma_f32_16x16x32_bf16(ah[i], bh[j], acc[i][j], 0, 0, 0);
        acc[i][j] = __builtin_amdgcn_mfma_f32_16x16x32_bf16(ah[i], bl[j], acc[i][j], 0, 0, 0);
        acc[i][j] = __builtin_amdgcn_mfma_f32_16x16x32_bf16(al[i], bh[j], acc[i][j], 0, 0, 0);
      }
    if (t + 1 < nt) {
      asm volatile("s_waitcnt vmcnt(0)" ::: "memory");
      __syncthreads();
      if constexpr (!APRE) {
        if (t + 2 < nt) {
          #pragma unroll
          for (int e = 0; e < 16; ++e) ac[e] = an[e];
        }
      }
      cur ^= 1;
    }
  }

  float* C = C0;
  int bnc = bn;
  if (bn >= NC) { C = C1; bnc = bn - NC; }

  #pragma unroll
  for (int i = 0; i < 4; ++i) {
    const int gr = bm + wm * 64 + i * 16 + quad * 4;
    #pragma unroll
    for (int j = 0; j < 4; ++j) {
      const int gc = bnc + wn * 64 + j * 16 + lr;
      float* cp = C + (size_t)gr * NC + gc;
      const float bv = (ACT == 1) ? bias[gc] : 0.f;
      #pragma unroll
      for (int r = 0; r < 4; ++r) {
        float v = acc[i][j][r];
        if (ACT == 1) v = softplus_f(v + bv);
        if (ATOMIC) atomicAdd(&cp[(size_t)r * NC], v);
        else        cp[(size_t)r * NC] = v;
      }
    }
  }
}

// GEMM1: [xc|z] = x @ W_in^T, A pre-split (APRE). Two half-grid launches
// (attribution). Standard mapping: x=col-tile, y=row-tile.
__global__ __launch_bounds__(256)
void gemm_in_bf16x3(const unsigned short* __restrict__ Ahi_g,
                    const unsigned short* __restrict__ Alo_g, int lda,
                    const unsigned short* __restrict__ Bhi,
                    const unsigned short* __restrict__ Blo,
                    float* __restrict__ C0, float* __restrict__ C1,
                    int NC, int K, int klen) {
  gemm_body<false, 0, true>(nullptr, Ahi_g, Alo_g, lda, Bhi, Blo, nullptr,
                            C0, C1, NC, K, klen,
                            blockIdx.y * 128, blockIdx.x * 128,
                            blockIdx.z * klen);
}

// GEMM4 (r11): out = y @ W_out^T, A = y bf16 planes (APRE), split-K=2,
// atomic. SWAPPED grid axes (x=row-tile, y=col-tile): XCD = bid%8 = x%8 ->
// each XCD owns 4 row-panels for ALL cols: A footprint 2MB/XCD (fits L2,
// fetched once) vs r10's every-XCD-reads-all-A (FETCH 139MB, 3.3x inputs).
__global__ __launch_bounds__(256)
void gemm_out_bf16x3(const unsigned short* __restrict__ Ahi_g,
                     const unsigned short* __restrict__ Alo_g, int lda,
                     const unsigned short* __restrict__ Bhi,
                     const unsigned short* __restrict__ Blo,
                     float* __restrict__ C0,
                     int NC, int K, int klen) {
  gemm_body<true, 0, true>(nullptr, Ahi_g, Alo_g, lda, Bhi, Blo, nullptr,
                           C0, C0, NC, K, klen,
                           blockIdx.x * 128, blockIdx.y * 128,
                           blockIdx.z * klen);
}

// ---- GEMM2: xp = xc2 @ W_xproj^T as MFMA bf16x3, APRE both sides ----
// r6-proven. M=4096, N=96 (tile 128x128, cols >=96 masked), K=2048 split 8.
__global__ __launch_bounds__(256)
void xproj_gemm_bf16x3(const unsigned short* __restrict__ Ahi_g,
                       const unsigned short* __restrict__ Alo_g,
                       const unsigned short* __restrict__ Bhi,
                       const unsigned short* __restrict__ Blo,
                       float* __restrict__ C, int klen) {
  __shared__ __align__(16) unsigned short Ah[2 * 128 * 32];
  __shared__ __align__(16) unsigned short Al[2 * 128 * 32];
  __shared__ __align__(16) unsigned short Bh[2 * 128 * 32];
  __shared__ __align__(16) unsigned short Bl[2 * 128 * 32];
  const int tid  = threadIdx.x;
  const int lane = tid & 63;
  const int wv   = tid >> 6;
  const int wm   = wv >> 1, wn = wv & 1;
  const int quad = lane >> 4, lr = lane & 15;
  const int bm = blockIdx.y * 128;
  const int kbeg = blockIdx.z * klen;

  int bOff[2], aOff[2], ldsO[2];
  #pragma unroll
  for (int j = 0; j < 2; ++j) {
    const int s   = (wv * 2 + j) * 64 + lane;
    const int row = s >> 2;
    const int c   = (s & 3) ^ ((row >> 1) & 3);
    bOff[j] = row * DI + c * 8;            // padded 128-row B, stride DI
    aOff[j] = (bm + row) * DI + c * 8;
    ldsO[j] = (wv * 2 + j) << 10;
  }
  int aRd[4], bRd[4];
  #pragma unroll
  for (int i = 0; i < 4; ++i) {
    const int ra = wm * 64 + i * 16 + lr;
    aRd[i] = (ra * 4 + (quad ^ ((ra >> 1) & 3))) << 4;
    const int rb = wn * 64 + i * 16 + lr;
    bRd[i] = (rb * 4 + (quad ^ ((rb >> 1) & 3))) << 4;
  }

  f32x4 acc[4][4];
  #pragma unroll
  for (int i = 0; i < 4; ++i)
    #pragma unroll
    for (int j = 0; j < 4; ++j)
      acc[i][j] = (f32x4){0.f, 0.f, 0.f, 0.f};

  const int nt = klen / 32;
  #pragma unroll
  for (int j = 0; j < 2; ++j) {
    gl2lds16(Ahi_g + (size_t)aOff[j] + kbeg, (char*)Ah + ldsO[j]);
    gl2lds16(Alo_g + (size_t)aOff[j] + kbeg, (char*)Al + ldsO[j]);
    gl2lds16(Bhi   + (size_t)bOff[j] + kbeg, (char*)Bh + ldsO[j]);
    gl2lds16(Blo   + (size_t)bOff[j] + kbeg, (char*)Bl + ldsO[j]);
  }
  asm volatile("s_waitcnt vmcnt(0)" ::: "memory");
  __syncthreads();

  int cur = 0;
  #pragma unroll 1
  for (int t = 0; t < nt; ++t) {
    const int km = kbeg + t * 32;
    if (t + 1 < nt) {
      const int nb = (cur ^ 1) * 8192;
      #pragma unroll
      for (int j = 0; j < 2; ++j) {
        gl2lds16(Ahi_g + (size_t)aOff[j] + km + 32, (char*)Ah + nb + ldsO[j]);
        gl2lds16(Alo_g + (size_t)aOff[j] + km + 32, (char*)Al + nb + ldsO[j]);
        gl2lds16(Bhi   + (size_t)bOff[j] + km + 32, (char*)Bh + nb + ldsO[j]);
        gl2lds16(Blo   + (size_t)bOff[j] + km + 32, (char*)Bl + nb + ldsO[j]);
      }
    }
    const int cb = cur * 8192;
    bf16x8 ah[4], al[4], bh[4], bl[4];
    #pragma unroll
    for (int i = 0; i < 4; ++i) {
      ah[i] = *(const bf16x8*)((const char*)Ah + cb + aRd[i]);
      al[i] = *(const bf16x8*)((const char*)Al + cb + aRd[i]);
      bh[i] = *(const bf16x8*)((const char*)Bh + cb + bRd[i]);
      bl[i] = *(const bf16x8*)((const char*)Bl + cb + bRd[i]);
    }
    #pragma unroll
    for (int i = 0; i < 4; ++i)
      #pragma unroll
      for (int j = 0; j < 4; ++j) {
        acc[i][j] = __builtin_amdgcn_mfma_f32_16x16x32_bf16(ah[i], bh[j], acc[i][j], 0, 0, 0);
        acc[i][j] = __builtin_amdgcn_mfma_f32_16x16x32_bf16(ah[i], bl[j], acc[i][j], 0, 0, 0);
        acc[i][j] = __builtin_amdgcn_mfma_f32_16x16x32_bf16(al[i], bh[j], acc[i][j], 0, 0, 0);
      }
    if (t + 1 < nt) {
      asm volatile("s_waitcnt vmcnt(0)" ::: "memory");
      __syncthreads();
      cur ^= 1;
    }
  }

  #pragma unroll
  for (int i = 0; i < 4; ++i) {
    const int gr = bm + wm * 64 + i * 16 + quad * 4;
    #pragma unroll
    for (int j = 0; j < 4; ++j) {
      const int gc = wn * 64 + j * 16 + lr;
      if (gc < NXP) {
        float* cp = C + (size_t)gr * NXP + gc;
        #pragma unroll
        for (int r = 0; r < 4; ++r)
          atomicAdd(&cp[(size_t)r * NXP], acc[i][j][r]);
      }
    }
  }
}

// Causal depthwise conv (width 4) + bias + SiLU.
// thread = 4 consecutive l x 4 d (float4); also emits bf16 hi/lo planes.
__global__ __launch_bounds__(256)
void conv_silu_kernel(const float* __restrict__ xc_raw, const float* __restrict__ cw,
                      const float* __restrict__ cb, float* __restrict__ xc2,
                      unsigned short* __restrict__ xc2hi,
                      unsigned short* __restrict__ xc2lo) {
  const int tid = blockIdx.x * 256 + threadIdx.x;   // NB*(LSEQ/4)*(DI/4)
  const int d4 = tid & (DI / 4 - 1);                // 9 bits
  const int lt = (tid >> 9) & (LSEQ / 4 - 1);       // 9 bits
  const int b  = tid >> 18;
  const int l0 = lt << 2;
  const size_t rowb = ((size_t)b * LSEQ + l0) * DI + d4 * 4;
  float4 v[7];
  #pragma unroll
  for (int j = 0; j < 7; ++j) {
    const int ls = l0 - 3 + j;
    v[j] = (ls >= 0) ? *(const float4*)(xc_raw + rowb + ((long long)j - 3) * DI)
                     : make_float4(0.f, 0.f, 0.f, 0.f);
  }
  const float4 bias = *(const float4*)(cb + d4 * 4);
  float4 w[4];
  #pragma unroll
  for (int k = 0; k < 4; ++k) w[k] = *(const float4*)(cw + (d4 * 4 + k) * 4);
  #pragma unroll
  for (int t = 0; t < 4; ++t) {
    float o[4];
    #pragma unroll
    for (int k = 0; k < 4; ++k) {
      float acc = fmaf(w[k].x, ((const float*)&v[t])[k], ((const float*)&bias)[k]);
      acc = fmaf(w[k].y, ((const float*)&v[t + 1])[k], acc);
      acc = fmaf(w[k].z, ((const float*)&v[t + 2])[k], acc);
      acc = fmaf(w[k].w, ((const float*)&v[t + 3])[k], acc);
      o[k] = silu_f(acc);
    }
    const size_t ob = rowb + (size_t)t * DI;
    *(float4*)(xc2 + ob) = make_float4(o[0], o[1], o[2], o[3]);
    ushort4 h, lo4;
    h.x = f2bf(o[0]); h.y = f2bf(o[1]); h.z = f2bf(o[2]); h.w = f2bf(o[3]);
    lo4.x = f2bf(o[0] - bf2f(h.x)); lo4.y = f2bf(o[1] - bf2f(h.y));
    lo4.z = f2bf(o[2] - bf2f(h.z)); lo4.w = f2bf(o[3] - bf2f(h.w));
    *(ushort4*)(xc2hi + ob) = h;
    *(ushort4*)(xc2lo + ob) = lo4;
  }
}

// ---- Pass 1 (lite): per-chunk summaries ONLY ----
__global__ __launch_bounds__(256)
void scan_chunk_kernel(const float* __restrict__ xc2, const float* __restrict__ dtb,
                       const float* __restrict__ xp, const float* __restrict__ A_log,
                       float* __restrict__ hloc, float* __restrict__ totdt) {
  __shared__ float sB[LC][DSTATE];   // 4 KB
  const int d = blockIdx.x * 256 + threadIdx.x;
  const int b = blockIdx.y;
  const int c = blockIdx.z;

  float A[DSTATE], h[DSTATE];
  #pragma unroll
  for (int n = 0; n < DSTATE; ++n) {
    A[n] = -__expf(A_log[(size_t)d * DSTATE + n]);
    h[n] = 0.f;
  }

  {
    const float* xpb = xp + ((size_t)b * LSEQ + (size_t)c * LC) * NXP + DTRANK;
    const int row = threadIdx.x >> 2, q = threadIdx.x & 3;
    *(float4*)&sB[row][q * 4] = *(const float4*)&xpb[(size_t)row * NXP + q * 4];
  }
  __syncthreads();

  const size_t cbase = ((size_t)b * LSEQ + (size_t)c * LC) * DI + d;
  float cum = 0.f;
  constexpr int U = 4;
  float cdt[U], cx[U];
  #pragma unroll
  for (int u = 0; u < U; ++u) {
    cdt[u] = dtb[cbase + (size_t)u * DI];
    cx[u]  = xc2[cbase + (size_t)u * DI];
  }

  #pragma unroll 1
  for (int g = 0; g < LC; g += U) {
    float ndt[U], nx[U];
    if (g + U < LC) {
      #pragma unroll
      for (int u = 0; u < U; ++u) {
        ndt[u] = dtb[cbase + (size_t)(g + U + u) * DI];
        nx[u]  = xc2[cbase + (size_t)(g + U + u) * DI];
      }
    }
    #pragma unroll
    for (int u = 0; u < U; ++u) {
      const int t = g + u;
      const float dt = cdt[u];
      const float dx = dt * cx[u];
      cum += dt;
      #pragma unroll
      for (int n = 0; n < DSTATE; ++n) {
        const float ab = __expf(dt * A[n]);
        h[n] = fmaf(ab, h[n], dx * sB[t][n]);
      }
    }
    if (g + U < LC) {
      #pragma unroll
      for (int u = 0; u < U; ++u) { cdt[u] = ndt[u]; cx[u] = nx[u]; }
    }
  }

  const size_t hbase = ((size_t)(b * CHUNKS + c)) * DSTATE * DI + d;
  #pragma unroll
  for (int n = 0; n < DSTATE; ++n) hloc[hbase + (size_t)n * DI] = h[n];
  totdt[((size_t)(b * CHUNKS + c)) * DI + d] = cum;
}

// Pass 2: carry propagation (in-place local-end -> carry-in). Unchanged.
__global__ __launch_bounds__(256)
void scan_carry_kernel(float* __restrict__ hloc, const float* __restrict__ totdt,
                       const float* __restrict__ A_log) {
  const int tid = blockIdx.x * 256 + threadIdx.x;   // NB*DSTATE*DI
  const int d = tid & (DI - 1);
  const int n = (tid >> 11) & 15;
  const int b = tid >> 15;
  const float An = -__expf(A_log[(size_t)d * DSTATE + n]);
  float h = 0.f;
  float le = hloc[((size_t)(b * CHUNKS) * DSTATE + n) * DI + d];
  float td = totdt[(size_t)(b * CHUNKS) * DI + d];
  for (int c = 0; c < CHUNKS; ++c) {
    const size_t ix = ((size_t)(b * CHUNKS + c) * DSTATE + n) * DI + d;
    float nle = 0.f, ntd = 0.f;
    if (c + 1 < CHUNKS) {
      nle = hloc[ix + (size_t)DSTATE * DI];
      ntd = totdt[(size_t)(b * CHUNKS + c + 1) * DI + d];
    }
    hloc[ix] = h;
    h = fmaf(__expf(An * td), h, le);
    le = nle; td = ntd;
  }
}

// ---- Pass 3: direct recurrence from carry-in; emit y as bf16 hi/lo ----
__global__ __launch_bounds__(256)
void scan_final_kernel(const float* __restrict__ xc2, const float* __restrict__ dtb,
                       const float* __restrict__ xp, const float* __restrict__ zbuf,
                       const float* __restrict__ A_log, const float* __restrict__ Dp,
                       const float* __restrict__ hloc,
                       unsigned short* __restrict__ yhi,
                       unsigned short* __restrict__ ylo) {
  __shared__ float sbc[LC][32];   // 8 KB: [t][0:16)=B, [16:32)=C
  const int tid = threadIdx.x;
  const int d = blockIdx.x * 256 + tid;
  const int b = blockIdx.y;
  const int c = blockIdx.z;

  float A[DSTATE], h[DSTATE];
  {
    const float* hp = hloc + ((size_t)(b * CHUNKS + c)) * DSTATE * DI + d;
    const float* ap = A_log + (size_t)d * DSTATE;
    #pragma unroll
    for (int n = 0; n < DSTATE; ++n) {
      A[n] = -__expf(ap[n]);
      h[n] = hp[(size_t)n * DI];     // carry-in state
    }
  }
  {
    const float* xpb = xp + ((size_t)b * LSEQ + (size_t)c * LC) * NXP + DTRANK;
    #pragma unroll
    for (int kk = 0; kk < 2; ++kk) {
      const int slot = tid + kk * 256;
      const int row = slot >> 3, q4 = (slot & 7) << 2;
      *(float4*)&sbc[row][q4] = *(const float4*)&xpb[(size_t)row * NXP + q4];
    }
  }
  __syncthreads();

  const float Dd = Dp[d];
  const size_t cbase = ((size_t)b * LSEQ + (size_t)c * LC) * DI + d;
  constexpr int U = 4;
  float cdt[U], cx[U], cz[U];
  #pragma unroll
  for (int u = 0; u < U; ++u) {
    cdt[u] = dtb[cbase + (size_t)u * DI];
    cx[u]  = xc2[cbase + (size_t)u * DI];
    cz[u]  = zbuf[cbase + (size_t)u * DI];
  }

  #pragma unroll 1
  for (int g = 0; g < LC; g += U) {
    float ndt[U], nx[U], nz[U];
    if (g + U < LC) {
      #pragma unroll
      for (int u = 0; u < U; ++u) {
        ndt[u] = dtb[cbase + (size_t)(g + U + u) * DI];
        nx[u]  = xc2[cbase + (size_t)(g + U + u) * DI];
        nz[u]  = zbuf[cbase + (size_t)(g + U + u) * DI];
      }
    }
    #pragma unroll
    for (int u = 0; u < U; ++u) {
      const int t = g + u;
      const float dt = cdt[u];
      const float dx = dt * cx[u];
      #pragma unroll
      for (int n = 0; n < DSTATE; ++n) {
        const float ab = __expf(dt * A[n]);
        h[n] = fmaf(ab, h[n], dx * sbc[t][n]);
      }
      float p[DSTATE];
      #pragma unroll
      for (int n = 0; n < DSTATE; ++n) p[n] = h[n] * sbc[t][DSTATE + n];
      #pragma unroll
      for (int s = 1; s < DSTATE; s <<= 1)
        #pragma unroll
        for (int n = 0; n < DSTATE; n += 2 * s) p[n] += p[n + s];
      const float yv = (p[0] + cx[u] * Dd) * silu_f(cz[u]);
      const size_t base = cbase + (size_t)t * DI;
      const unsigned short hh = f2bf(yv);
      yhi[base] = hh;
      ylo[base] = f2bf(yv - bf2f(hh));
    }
    if (g + U < LC) {
      #pragma unroll
      for (int u = 0; u < U; ++u) { cdt[u] = ndt[u]; cx[u] = nx[u]; cz[u] = nz[u]; }
    }
  }
}

extern "C" void kernel_launch(void* const* d_in, const int* in_sizes, int n_in,
                              void* d_out, int out_size, void* d_ws, size_t ws_size,
                              hipStream_t stream) {
  const float* x      = (const float*)d_in[0];
  const float* W_in   = (const float*)d_in[1];
  const float* conv_w = (const float*)d_in[2];
  const float* conv_b = (const float*)d_in[3];
  const float* W_xproj= (const float*)d_in[4];
  const float* W_dt   = (const float*)d_in[5];
  const float* b_dt   = (const float*)d_in[6];
  const float* A_log  = (const float*)d_in[7];
  const float* Dp     = (const float*)d_in[8];
  const float* W_out  = (const float*)d_in[9];
  float* out = (float*)d_out;
  float* ws  = (float*)d_ws;

  // ws layout (floats), ~154 MB:
  //   xc_raw[SEG] | zbuf[SEG] | xc2[SEG] | dtb[SEG] | xp | hloc | totdt | pools
  // Overlays (time-disjoint):
  //   Whi/Wlo over dtb        — consumed by GEMM1 (dtb written later by dt_gemm).
  //   xc2hi/xc2lo over dtb    — conv..xproj window, dead before dt_gemm.
  //   xhi/xlo over xc2        — prep..GEMM1 window; conv overwrites xc2.
  //   yhi/ylo over xc_raw     — scan_final output, consumed by GEMM4 APRE.
  const size_t SEG = (size_t)NB * LSEQ * DI;            // 8,388,608
  float* xc_raw = ws;
  float* zbuf   = ws + SEG;
  float* xc2    = ws + 2 * SEG;
  float* dtb    = ws + 3 * SEG;
  float* xp     = ws + 4 * SEG;                         // 393,216
  float* hloc   = xp + (size_t)MROWS * NXP;             // 2,097,152
  float* totdt  = hloc + (size_t)NB * CHUNKS * DSTATE * DI;  // 131,072
  float* wpool  = totdt + (size_t)NB * CHUNKS * DI;

  unsigned short* Whi = (unsigned short*)dtb;           // overlay (dead before conv)
  unsigned short* Wlo = Whi + (size_t)2 * DI * DMODEL;

  unsigned short* xc2hi = (unsigned short*)dtb;         // overlay (conv..xproj window)
  unsigned short* xc2lo = xc2hi + (size_t)MROWS * DI;

  unsigned short* xhi = (unsigned short*)xc2;           // overlay (dead until conv)
  unsigned short* xlo = xhi + (size_t)MROWS * DMODEL;

  unsigned short* yhi = (unsigned short*)xc_raw;        // overlay (scan_final..GEMM4)
  unsigned short* ylo = yhi + (size_t)MROWS * DI;

  unsigned short* Wohi = (unsigned short*)wpool;        // 2,097,152 ushort
  unsigned short* Wolo = Wohi + (size_t)DMODEL * DI;
  unsigned short* wdhi = Wolo + (size_t)DMODEL * DI;    // 131,072 ushort
  unsigned short* wdlo = wdhi + (size_t)DI * DTRANK;
  unsigned short* wxhi = wdlo + (size_t)DI * DTRANK;    // 262,144 ushort (padded 128xDI)
  unsigned short* wxlo = wxhi + (size_t)128 * DI;

  dim3 blk(256);

  // Prep: weight + x splits (incl. padded W_xproj), zero xp and out
  const int prep_blocks = (2*DI*DMODEL/4 + DI*DTRANK/4 + DMODEL*DI/4
                           + MROWS*DMODEL/4 + 128*DI/4
                           + MROWS*NXP/4 + MROWS*DMODEL/4) / 256;
  prep_kernel<<<prep_blocks, blk, 0, stream>>>(
      W_in, W_dt, W_out, x, W_xproj, Whi, Wlo, wdhi, wdlo, Wohi, Wolo,
      xhi, xlo, wxhi, wxlo, xp, out);

  // GEMM1 fused: [xc | z] = x @ W_in^T  (128^2, A pre-split; K=1024)
  // Two half-grid launches (rows 0..2047 / 2048..4095) for rocprof
  // attribution — offset A planes and C pointers; body unchanged.
  const size_t rowHalf = (size_t)(MROWS / 2);
  gemm_in_bf16x3<<<dim3(2*DI/128, MROWS/256, 1), blk, 0, stream>>>(
      xhi, xlo, DMODEL, Whi, Wlo, xc_raw, zbuf, DI, DMODEL, DMODEL);
  gemm_in_bf16x3<<<dim3(2*DI/128, MROWS/256, 1), blk, 0, stream>>>(
      xhi + rowHalf * DMODEL, xlo + rowHalf * DMODEL, DMODEL, Whi, Wlo,
      xc_raw + rowHalf * DI, zbuf + rowHalf * DI, DI, DMODEL, DMODEL);

  // conv + bias + SiLU (4l x 4d per thread) + bf16 hi/lo planes of xc2
  conv_silu_kernel<<<(NB*(LSEQ/4)*(DI/4))/256, blk, 0, stream>>>(
      xc_raw, conv_w, conv_b, xc2, xc2hi, xc2lo);

  // GEMM2: xp = xc2 @ W_xproj^T — MFMA bf16x3, split-K=8 atomic (xp zeroed)
  xproj_gemm_bf16x3<<<dim3(1, MROWS/128, 8), blk, 0, stream>>>(
      xc2hi, xc2lo, wxhi, wxlo, xp, DI/8);

  // GEMM3: dt = softplus(dt_lr @ W_dt^T + b_dt) — dedicated LDS-free kernel
  dt_gemm_kernel<<<dim3(DI/128, MROWS/128, 1), blk, 0, stream>>>(
      xp, wdhi, wdlo, b_dt, dtb);

  // Scan: summaries -> carries -> direct recurrence emitting y bf16 planes
  scan_chunk_kernel<<<dim3(DI/256, NB, CHUNKS), blk, 0, stream>>>(
      xc2, dtb, xp, A_log, hloc, totdt);
  scan_carry_kernel<<<(NB*DI*DSTATE)/256, blk, 0, stream>>>(hloc, totdt, A_log);
  scan_final_kernel<<<dim3(DI/256, NB, CHUNKS), blk, 0, stream>>>(
      xc2, dtb, xp, zbuf, A_log, Dp, hloc, yhi, ylo);

  // GEMM4: out = y @ W_out^T — A = y bf16 planes (APRE), split-K=2, atomic
  // (out zeroed in prep). Grid SWAPPED: (row-tiles=32, col-tiles=8, 2).
  gemm_out_bf16x3<<<dim3(MROWS/128, DMODEL/128, 2), blk, 0, stream>>>(
      yhi, ylo, DI, Wohi, Wolo, out, DMODEL, DI, DI/2);
}